// Round 13
// baseline (1218.436 us; speedup 1.0000x reference)
//
#include <hip/hip_runtime.h>

#define NG 50000
#define NR 12000
#define EPS_N 50000
#define ELR_N 5000
#define E1_N 150000
#define E2_N 150000
#define GN_EPS_F 1e-5f
#define SCAN_CHUNK 4096
#define WST 136   // wave-LDS tile row stride (bf16 elems)

typedef __attribute__((ext_vector_type(8))) __bf16 bf16x8;
typedef __attribute__((ext_vector_type(4))) float f32x4;

__device__ __forceinline__ bf16x8 cvt8(const float* __restrict__ p) {
    float4 x0 = *reinterpret_cast<const float4*>(p);
    float4 x1 = *reinterpret_cast<const float4*>(p + 4);
    bf16x8 a;
    a[0] = (__bf16)x0.x; a[1] = (__bf16)x0.y; a[2] = (__bf16)x0.z; a[3] = (__bf16)x0.w;
    a[4] = (__bf16)x1.x; a[5] = (__bf16)x1.y; a[6] = (__bf16)x1.z; a[7] = (__bf16)x1.w;
    return a;
}

// ---------- manual OCP e4m3 quantizer (values are post-relu, >= 0) ----------
__device__ __forceinline__ unsigned f32_to_fp8(float f) {
    f = fminf(f, 448.f);
    unsigned bits = __float_as_uint(f);
    int e = (int)((bits >> 23) & 0xff) - 127;
    if (e < -9) return 0u;
    if (e < -6) {                       // denormal: round(f * 2^9), carry ok
        return (unsigned)(int)(f * 512.f + 0.5f);
    }
    unsigned m = (bits >> 20) & 7;
    unsigned r = (bits >> 19) & 1;
    unsigned em = ((unsigned)(e + 7) << 3) | m;
    em += r;
    if (em > 0x7Eu) em = 0x7Eu;        // clamp below NaN (max 448)
    return em;
}

__device__ __forceinline__ float fp8_to_f32(unsigned b) {
    unsigned em = b & 0x7fu;
    float mag = (em >= 8u)
        ? __uint_as_float((((em >> 3) + 120u) << 23) | ((em & 7u) << 20))
        : (float)em * 0.001953125f;     // denormal: em * 2^-9
    return (b & 0x80u) ? -mag : mag;
}

// ====== weight prep: f32 -> fragment-major bf16 (global, coalesced reads) ===
struct PrepTab { const float* src[80]; int stride[80]; int n; };

__global__ void prepw_k(PrepTab tab, __bf16* __restrict__ wbuf)
{
    int t = blockIdx.x * 256 + threadIdx.x;
    int w = t >> 11;
    if (w >= tab.n) return;
    int rr = t & 2047;
    int chunk = rr >> 6, l = rr & 63;
    int wn = chunk >> 4, ks = (chunk >> 2) & 3, ni = chunk & 3;
    int c = wn * 64 + ni * 16 + (l & 15);
    int kb = (ks * 4 + (l >> 4)) * 8;
    const float* s = tab.src[w] + (size_t)c * tab.stride[w] + kb;
    bf16x8 o;
    #pragma unroll
    for (int e = 0; e < 8; ++e) o[e] = (__bf16)s[e];
    *reinterpret_cast<bf16x8*>(wbuf + (size_t)w * 16384 + rr * 8) = o;
}

// ============================ CSR construction =============================
__global__ void hist14_k(const int* __restrict__ ps_u, const int* __restrict__ lr_u,
                         int* __restrict__ cnt)
{
    int t = blockIdx.x * 256 + threadIdx.x;
    const int total = 12 * EPS_N + 2 * ELR_N;
    if (t >= total) return;
    int k, u;
    if (t < 12 * EPS_N) { k = t / EPS_N; u = ps_u[t]; }
    else { int r = t - 12 * EPS_N; k = 12 + r / ELR_N; u = lr_u[r]; }
    atomicAdd(&cnt[k * NG + u], 1);
}

__global__ void fill14_k(const int* __restrict__ ps_u, const int* __restrict__ ps_v,
                         const int* __restrict__ lr_u, const int* __restrict__ lr_v,
                         int* __restrict__ head, int* __restrict__ col)
{
    int t = blockIdx.x * 256 + threadIdx.x;
    const int total = 12 * EPS_N + 2 * ELR_N;
    if (t >= total) return;
    int k, u, v;
    if (t < 12 * EPS_N) { k = t / EPS_N; u = ps_u[t]; v = ps_v[t]; }
    else { int r = t - 12 * EPS_N; k = 12 + r / ELR_N; u = lr_u[r]; v = lr_v[r]; }
    int pos = atomicAdd(&head[k * NG + u], 1);
    col[pos] = v;
}

__global__ void histE_k(const int* __restrict__ wi, int n, int* __restrict__ cnt)
{
    int t = blockIdx.x * 256 + threadIdx.x;
    if (t >= n) return;
    atomicAdd(&cnt[wi[t]], 1);
}

__global__ void fillE_k(const int* __restrict__ wi, int n,
                        int* __restrict__ head, int* __restrict__ col)
{
    int t = blockIdx.x * 256 + threadIdx.x;
    if (t >= n) return;
    int pos = atomicAdd(&head[wi[t]], 1);
    col[pos] = t;
}

__global__ void scan1_k(const int* __restrict__ in, int n, int* __restrict__ bsum)
{
    __shared__ int sm[4];
    int base = blockIdx.x * SCAN_CHUNK;
    int s = 0;
    for (int i = threadIdx.x; i < SCAN_CHUNK; i += 256) {
        int idx = base + i;
        s += (idx < n) ? in[idx] : 0;
    }
    #pragma unroll
    for (int off = 1; off < 64; off <<= 1) s += __shfl_xor(s, off);
    if ((threadIdx.x & 63) == 0) sm[threadIdx.x >> 6] = s;
    __syncthreads();
    if (threadIdx.x == 0) bsum[blockIdx.x] = sm[0] + sm[1] + sm[2] + sm[3];
}

__global__ void scan2_k(int* __restrict__ bsum, int nb)
{
    if (threadIdx.x == 0) {
        int acc = 0;
        for (int i = 0; i < nb; ++i) { int t = bsum[i]; bsum[i] = acc; acc += t; }
    }
}

__global__ void scan3_k(const int* __restrict__ in, int n,
                        const int* __restrict__ bsum, int* __restrict__ outp)
{
    __shared__ int sm[256];
    int base = blockIdx.x * SCAN_CHUNK;
    int loc[16]; int s = 0;
    #pragma unroll
    for (int i = 0; i < 16; ++i) {
        int idx = base + threadIdx.x * 16 + i;
        loc[i] = (idx < n) ? in[idx] : 0; s += loc[i];
    }
    sm[threadIdx.x] = s; __syncthreads();
    for (int off = 1; off < 256; off <<= 1) {
        int v = (threadIdx.x >= off) ? sm[threadIdx.x - off] : 0;
        __syncthreads();
        sm[threadIdx.x] += v;
        __syncthreads();
    }
    int tp = (threadIdx.x ? sm[threadIdx.x - 1] : 0) + bsum[blockIdx.x];
    #pragma unroll
    for (int i = 0; i < 16; ++i) {
        int idx = base + threadIdx.x * 16 + i;
        if (idx < n) outp[idx] = tp;
        tp += loc[i];
        if (idx == n - 1) outp[n] = tp;
    }
}

// ================ wave-autonomous GEMM helpers (BM=16 per wave) =============
__device__ __forceinline__ void mfma16(f32x4 (&acc)[8], const bf16x8 (&a)[4],
                                       const __bf16* __restrict__ gw, int lane)
{
    const __bf16* gwb = gw + lane * 8;
    #pragma unroll
    for (int ks = 0; ks < 4; ++ks) {
        #pragma unroll
        for (int n2 = 0; n2 < 8; ++n2) {
            const int chunk = (n2 >> 2) * 16 + ks * 4 + (n2 & 3);
            bf16x8 b = *reinterpret_cast<const bf16x8*>(gwb + chunk * 512);
            acc[n2] = __builtin_amdgcn_mfma_f32_16x16x32_bf16(a[ks], b, acc[n2], 0, 0, 0);
        }
    }
}

__device__ __forceinline__ void ss_to_frags(const float (&ss)[32], bf16x8 (&a)[4])
{
    #pragma unroll
    for (int ks = 0; ks < 4; ++ks)
        #pragma unroll
        for (int i = 0; i < 8; ++i)
            a[ks][i] = (__bf16)ss[ks * 8 + i];
}

__device__ __forceinline__ void gn_mi(const f32x4 (&acc)[8], float (&m)[4], float (&inv)[4])
{
    #pragma unroll
    for (int reg = 0; reg < 4; ++reg) {
        float s = 0.f, q = 0.f;
        #pragma unroll
        for (int n2 = 0; n2 < 8; ++n2) { float v = acc[n2][reg]; s += v; q = fmaf(v, v, q); }
        #pragma unroll
        for (int off = 1; off < 16; off <<= 1) {
            s += __shfl_xor(s, off);
            q += __shfl_xor(q, off);
        }
        m[reg] = s * (1.f / 128.f);
        inv[reg] = rsqrtf(fmaxf(q * (1.f / 128.f) - m[reg] * m[reg], 0.f) + GN_EPS_F);
    }
}

__device__ __forceinline__ void gn_relayout(const f32x4 (&acc)[8], const float* __restrict__ sb,
                                            __bf16* wl, bf16x8 (&a)[4], int r16, int kq)
{
    float m[4], inv[4];
    gn_mi(acc, m, inv);
    #pragma unroll
    for (int reg = 0; reg < 4; ++reg) {
        #pragma unroll
        for (int n2 = 0; n2 < 8; ++n2) {
            const int colc = n2 * 16 + r16;
            float y = (acc[n2][reg] - m[reg]) * inv[reg] * sb[colc] + sb[128 + colc];
            wl[(kq * 4 + reg) * WST + colc] = (__bf16)fmaxf(y, 0.f);
        }
    }
    #pragma unroll
    for (int ks = 0; ks < 4; ++ks)
        a[ks] = *reinterpret_cast<const bf16x8*>(wl + r16 * WST + ks * 32 + kq * 8);
}

// ============ edgefull: h[e] = relu(gn(ctx[hi]@c1A + dist@c1B, sb)) =========
template<typename CT>
__launch_bounds__(128, 3)
__global__ void edgefull_k(const int* __restrict__ hi_idx, const int* __restrict__ wi_idx,
                           const CT* __restrict__ ctxfeat,
                           const float* __restrict__ cpose, const float* __restrict__ tpose,
                           const float* __restrict__ rpw, const float* __restrict__ rpb,
                           const __bf16* __restrict__ wc1A, const __bf16* __restrict__ wc1B,
                           const float* __restrict__ sb,
                           __bf16* __restrict__ hout, int M)
{
    __shared__ float rw[640];
    const int tid = threadIdx.x, lane = tid & 63, wv = tid >> 6;
    const int r16 = lane & 15, kq = lane >> 4;
    const int wbase = blockIdx.x * 32 + wv * 16;
    const int erow = wbase + r16;
    const int ec = erow < M ? erow : M - 1;

    for (int i = tid; i < 640; i += 128)
        rw[i] = (i < 512) ? rpw[i] : rpb[i - 512];
    __syncthreads();

    const int hi = hi_idx[ec], wi = wi_idx[ec];
    float4 cp = *reinterpret_cast<const float4*>(cpose + (size_t)hi * 4);
    float4 tp = *reinterpret_cast<const float4*>(tpose + (size_t)wi * 4);
    const float d0 = cp.x - tp.x, d1 = cp.y - tp.y, d2 = cp.z - tp.z, d3 = cp.w - tp.w;

    f32x4 acc[8];
    #pragma unroll
    for (int n2 = 0; n2 < 8; ++n2) acc[n2] = (f32x4){0.f, 0.f, 0.f, 0.f};

    {   // ctx[hi] @ c1A
        bf16x8 a[4];
        const CT* sp = ctxfeat + (size_t)hi * 128 + kq * 8;
        #pragma unroll
        for (int ks = 0; ks < 4; ++ks) {
            if constexpr (sizeof(CT) == 4) a[ks] = cvt8((const float*)sp + ks * 32);
            else a[ks] = *reinterpret_cast<const bf16x8*>((const __bf16*)sp + ks * 32);
        }
        mfma16(acc, a, wc1A, lane);
    }
    {   // dist @ c1B (A built in-register)
        bf16x8 a[4];
        #pragma unroll
        for (int ks = 0; ks < 4; ++ks)
            #pragma unroll
            for (int i = 0; i < 8; ++i) {
                const int k = ks * 32 + kq * 8 + i;
                float4 w4 = *reinterpret_cast<const float4*>(&rw[k * 4]);
                float d = fmaf(d0, w4.x, fmaf(d1, w4.y, fmaf(d2, w4.z,
                          fmaf(d3, w4.w, rw[512 + k]))));
                a[ks][i] = (__bf16)fmaxf(d, 0.f);
            }
        mfma16(acc, a, wc1B, lane);
    }

    float m[4], inv[4];
    gn_mi(acc, m, inv);
    #pragma unroll
    for (int reg = 0; reg < 4; ++reg) {
        const int crow = wbase + kq * 4 + reg;
        if (crow < M) {
            __bf16* dp = hout + (size_t)crow * 128 + r16;
            #pragma unroll
            for (int n2 = 0; n2 < 8; ++n2) {
                const int colc = n2 * 16 + r16;
                float y = (acc[n2][reg] - m[reg]) * inv[reg] * sb[colc] + sb[128 + colc];
                dp[n2 * 16] = (__bf16)fmaxf(y, 0.f);
            }
        }
    }
}

// ======= fusedlayer: R9 structure; neighbor gathers read the fp8 copy =======
struct FW { const __bf16* w[16]; };   // 0..11 ps, 12 left, 13 right, 14 ctr, 15 ctr2

__launch_bounds__(128, 3)
__global__ void fusedlayer_k(const __bf16* __restrict__ feat,
                             const unsigned char* __restrict__ feat8,
                             const int* __restrict__ rp, const int* __restrict__ col,
                             FW fw, const float* __restrict__ gn1,
                             const float* __restrict__ gn2,
                             __bf16* __restrict__ outp,
                             unsigned char* __restrict__ out8, int M)
{
    __shared__ __bf16 wl[2][16 * WST];
    const int tid = threadIdx.x, lane = tid & 63, wv = tid >> 6;
    const int r16 = lane & 15, kq = lane >> 4;
    const int wbase = blockIdx.x * 32 + wv * 16;
    const int wrow = (wbase + r16) < M ? (wbase + r16) : M - 1;

    f32x4 acc[8];
    #pragma unroll
    for (int n2 = 0; n2 < 8; ++n2) acc[n2] = (f32x4){0.f, 0.f, 0.f, 0.f};

    #pragma unroll
    for (int j = 0; j < 15; ++j) {
        float ss[32];
        #pragma unroll
        for (int i = 0; i < 32; ++i) ss[i] = 0.f;
        if (j == 14) {
            const __bf16* sp = feat + (size_t)wrow * 128 + kq * 8;
            #pragma unroll
            for (int ks = 0; ks < 4; ++ks) {
                bf16x8 h = *reinterpret_cast<const bf16x8*>(sp + ks * 32);
                #pragma unroll
                for (int i = 0; i < 8; ++i) ss[ks * 8 + i] = (float)h[i];
            }
        } else {
            const int b = rp[j * M + wrow], e = rp[j * M + wrow + 1];
            for (int t2 = b; t2 < e; ++t2) {
                const unsigned char* sp = feat8 + (size_t)col[t2] * 128 + kq * 8;
                #pragma unroll
                for (int ks = 0; ks < 4; ++ks) {
                    unsigned long long u8 =
                        *reinterpret_cast<const unsigned long long*>(sp + ks * 32);
                    #pragma unroll
                    for (int i = 0; i < 8; ++i)
                        ss[ks * 8 + i] += fp8_to_f32((unsigned)(u8 >> (8 * i)) & 0xffu);
                }
            }
        }
        bf16x8 a[4];
        ss_to_frags(ss, a);
        mfma16(acc, a, fw.w[j], lane);
    }

    // GN1 + relu -> wave LDS -> A-frags; ctr2 GEMM
    bf16x8 a2[4];
    gn_relayout(acc, gn1, wl[wv], a2, r16, kq);
    f32x4 acc2[8];
    #pragma unroll
    for (int n2 = 0; n2 < 8; ++n2) acc2[n2] = (f32x4){0.f, 0.f, 0.f, 0.f};
    mfma16(acc2, a2, fw.w[15], lane);

    // GN2 + residual + relu -> out (bf16 + fp8 shadow)
    float m[4], inv[4];
    gn_mi(acc2, m, inv);
    #pragma unroll
    for (int reg = 0; reg < 4; ++reg) {
        const int crow = wbase + kq * 4 + reg;
        if (crow < M) {
            __bf16* dp = outp + (size_t)crow * 128 + r16;
            unsigned char* d8 = out8 + (size_t)crow * 128 + r16;
            const __bf16* rs = feat + (size_t)crow * 128 + r16;
            #pragma unroll
            for (int n2 = 0; n2 < 8; ++n2) {
                const int colc = n2 * 16 + r16;
                float y = (acc2[n2][reg] - m[reg]) * inv[reg] * gn2[colc] + gn2[128 + colc];
                y += (float)rs[n2 * 16];
                y = fmaxf(y, 0.f);
                dp[n2 * 16] = (__bf16)y;
                d8[n2 * 16] = (unsigned char)f32_to_fp8(y);
            }
        }
    }
}

// ============= lptail: lane_pooling tail (R9 + optional fp8 shadow) =========
template<bool LP2>
__launch_bounds__(128, 3)
__global__ void lptail_k(const __bf16* __restrict__ hsrc,
                         const int* __restrict__ rp, const int* __restrict__ col,
                         const float* __restrict__ roi,
                         const __bf16* __restrict__ wc2, const __bf16* __restrict__ winW,
                         const __bf16* __restrict__ wm1, const __bf16* __restrict__ wm2,
                         const float* __restrict__ ngn, const float* __restrict__ m1gn,
                         const float* __restrict__ m2gn,
                         void* __restrict__ outp,
                         unsigned char* __restrict__ out8, int M)
{
    __shared__ __bf16 wl[2][16 * WST];
    const int tid = threadIdx.x, lane = tid & 63, wv = tid >> 6;
    const int r16 = lane & 15, kq = lane >> 4;
    const int wbase = blockIdx.x * 32 + wv * 16;
    const int wrow = (wbase + r16) < M ? (wbase + r16) : M - 1;

    f32x4 acc[8];
    #pragma unroll
    for (int n2 = 0; n2 < 8; ++n2) acc[n2] = (f32x4){0.f, 0.f, 0.f, 0.f};

    {   // (Σ h) @ c2
        float ss[32];
        #pragma unroll
        for (int i = 0; i < 32; ++i) ss[i] = 0.f;
        const int b = rp[wrow], e = rp[wrow + 1];
        for (int t2 = b; t2 < e; ++t2) {
            const __bf16* sp = hsrc + (size_t)col[t2] * 128 + kq * 8;
            #pragma unroll
            for (int ks = 0; ks < 4; ++ks) {
                bf16x8 h = *reinterpret_cast<const bf16x8*>(sp + ks * 32);
                #pragma unroll
                for (int i = 0; i < 8; ++i) ss[ks * 8 + i] += (float)h[i];
            }
        }
        bf16x8 a[4];
        ss_to_frags(ss, a);
        mfma16(acc, a, wc2, lane);
    }
    if (LP2) {   // + roi @ input_w
        bf16x8 a[4];
        const float* sp = roi + (size_t)wrow * 128 + kq * 8;
        #pragma unroll
        for (int ks = 0; ks < 4; ++ks) a[ks] = cvt8(sp + ks * 32);
        mfma16(acc, a, winW, lane);
    }

    {   // relu(gn(.,ngn)) @ m1
        bf16x8 a[4];
        gn_relayout(acc, ngn, wl[wv], a, r16, kq);
        #pragma unroll
        for (int n2 = 0; n2 < 8; ++n2) acc[n2] = (f32x4){0.f, 0.f, 0.f, 0.f};
        mfma16(acc, a, wm1, lane);
    }
    {   // relu(gn(.,m1gn)) @ m2
        bf16x8 a[4];
        gn_relayout(acc, m1gn, wl[wv], a, r16, kq);
        #pragma unroll
        for (int n2 = 0; n2 < 8; ++n2) acc[n2] = (f32x4){0.f, 0.f, 0.f, 0.f};
        mfma16(acc, a, wm2, lane);
    }

    float m[4], inv[4];
    gn_mi(acc, m, inv);
    #pragma unroll
    for (int reg = 0; reg < 4; ++reg) {
        const int crow = wbase + kq * 4 + reg;
        if (crow < M) {
            #pragma unroll
            for (int n2 = 0; n2 < 8; ++n2) {
                const int colc = n2 * 16 + r16;
                float y = (acc[n2][reg] - m[reg]) * inv[reg] * m2gn[colc] + m2gn[128 + colc];
                if (LP2) {
                    y += roi[(size_t)crow * 128 + colc];
                    ((float*)outp)[(size_t)crow * 128 + colc] = fmaxf(y, 0.f);
                } else {
                    y = fmaxf(y, 0.f);
                    ((__bf16*)outp)[(size_t)crow * 128 + colc] = (__bf16)y;
                    out8[(size_t)crow * 128 + colc] = (unsigned char)f32_to_fp8(y);
                }
            }
        }
    }
}

// ===========================================================================
extern "C" void kernel_launch(void* const* d_in, const int* in_sizes, int n_in,
                              void* d_out, int out_size, void* d_ws, size_t ws_size,
                              hipStream_t stream)
{
    const float* roi_feat   = (const float*)d_in[0];
    const float* graph_pose = (const float*)d_in[1];
    const float* roi_pose   = (const float*)d_in[2];
    const float* lp_input_w = (const float*)d_in[3];
    const float* lp_rpw     = (const float*)d_in[4];
    const float* lp_rpb     = (const float*)d_in[5];
    const float* lp_c1w     = (const float*)d_in[6];
    const float* lp_c1gn    = (const float*)d_in[7];
    const float* lp_c2w     = (const float*)d_in[8];
    const float* lp_m1w     = (const float*)d_in[9];
    const float* lp_m1gn    = (const float*)d_in[10];
    const float* lp_m2w     = (const float*)d_in[11];
    const float* lp_m2gn    = (const float*)d_in[12];
    const float* lp_ngn     = (const float*)d_in[13];
    const float* f_ctrw     = (const float*)d_in[14];
    const float* f_psw      = (const float*)d_in[15];
    const float* f_lw       = (const float*)d_in[16];
    const float* f_rw       = (const float*)d_in[17];
    const float* f_ngn      = (const float*)d_in[18];
    const float* f_c2w      = (const float*)d_in[19];
    const float* f_c2gn     = (const float*)d_in[20];
    const int* e1_hi = (const int*)d_in[21];
    const int* e1_wi = (const int*)d_in[22];
    const int* e2_hi = (const int*)d_in[23];
    const int* e2_wi = (const int*)d_in[24];
    const int* ps_u  = (const int*)d_in[25];
    const int* ps_v  = (const int*)d_in[26];
    const int* lr_u  = (const int*)d_in[27];
    const int* lr_v  = (const int*)d_in[28];
    float* out = (float*)d_out;

    // ---- workspace (~90 MB) ----
    __bf16* gA   = (__bf16*)d_ws;                       // NG*128
    __bf16* gB   = gA + (size_t)NG * 128;               // NG*128
    __bf16* hbuf = gB + (size_t)NG * 128;               // E1_N*128
    __bf16* wbuf = hbuf + (size_t)E1_N * 128;           // 80*16384
    unsigned char* g8A = (unsigned char*)(wbuf + (size_t)80 * 16384); // NG*128 B
    unsigned char* g8B = g8A + (size_t)NG * 128;                      // NG*128 B
    int* ip      = (int*)(g8B + (size_t)NG * 128);
    int* cnt14   = ip;             ip += 14 * NG;
    int* rp14    = ip;             ip += 14 * NG + 1;
    int* col14   = ip;             ip += 12 * EPS_N + 2 * ELR_N;
    int* cntE1   = ip;             ip += NG;
    int* rpE1    = ip;             ip += NG + 1;
    int* colE1   = ip;             ip += E1_N;
    int* cntE2   = ip;             ip += NR;
    int* rpE2    = ip;             ip += NR + 1;
    int* colE2   = ip;             ip += E2_N;
    int* bsum    = ip;             ip += 256;

    dim3 blk(256), blk128(128);
    const dim3 gNG32((NG + 31) / 32), gNR32((NR + 31) / 32), gE32((E1_N + 31) / 32);
    const int NE14 = 12 * EPS_N + 2 * ELR_N;
    const dim3 gH14((NE14 + 255) / 256);

    // ---------------- weight prep ----------------
    PrepTab tab; int nw = 0;
    auto addw = [&](const float* p, int s) { tab.src[nw] = p; tab.stride[nw] = s; ++nw; };
    addw(lp_c1w, 256);                 // 0 c1A_0
    addw(lp_c1w + 128, 256);           // 1 c1B_0
    addw(lp_c1w + 32768, 256);         // 2 c1A_1
    addw(lp_c1w + 32768 + 128, 256);   // 3 c1B_1
    addw(lp_input_w + 16384, 128);     // 4 input_w[1]
    addw(lp_c2w, 128); addw(lp_c2w + 16384, 128);   // 5,6
    addw(lp_m1w, 128); addw(lp_m1w + 16384, 128);   // 7,8
    addw(lp_m2w, 128); addw(lp_m2w + 16384, 128);   // 9,10
    for (int i = 0; i < 4; ++i) addw(f_ctrw + (size_t)i * 16384, 128);      // 11..14
    for (int i = 0; i < 4; ++i)
        for (int k = 0; k < 12; ++k) addw(f_psw + ((size_t)i * 12 + k) * 16384, 128);
    for (int i = 0; i < 4; ++i) addw(f_lw + (size_t)i * 16384, 128);        // 63..66
    for (int i = 0; i < 4; ++i) addw(f_rw + (size_t)i * 16384, 128);        // 67..70
    for (int i = 0; i < 4; ++i) addw(f_c2w + (size_t)i * 16384, 128);       // 71..74
    tab.n = nw;
    auto wb = [&](int idx) { return (const __bf16*)(wbuf + (size_t)idx * 16384); };
    prepw_k<<<dim3((nw * 2048 + 255) / 256), blk, 0, stream>>>(tab, wbuf);

    // ---------------- CSR builds ----------------
    hipMemsetAsync(cnt14, 0, (size_t)14 * NG * 4, stream);
    hist14_k<<<gH14, blk, 0, stream>>>(ps_u, lr_u, cnt14);
    {
        int n = 14 * NG, nb = (n + SCAN_CHUNK - 1) / SCAN_CHUNK;
        scan1_k<<<nb, blk, 0, stream>>>(cnt14, n, bsum);
        scan2_k<<<1, blk, 0, stream>>>(bsum, nb);
        scan3_k<<<nb, blk, 0, stream>>>(cnt14, n, bsum, rp14);
    }
    hipMemcpyAsync(cnt14, rp14, (size_t)14 * NG * 4, hipMemcpyDeviceToDevice, stream);
    fill14_k<<<gH14, blk, 0, stream>>>(ps_u, ps_v, lr_u, lr_v, cnt14, col14);

    hipMemsetAsync(cntE1, 0, (size_t)NG * 4, stream);
    histE_k<<<(E1_N + 255) / 256, blk, 0, stream>>>(e1_wi, E1_N, cntE1);
    {
        int n = NG, nb = (n + SCAN_CHUNK - 1) / SCAN_CHUNK;
        scan1_k<<<nb, blk, 0, stream>>>(cntE1, n, bsum);
        scan2_k<<<1, blk, 0, stream>>>(bsum, nb);
        scan3_k<<<nb, blk, 0, stream>>>(cntE1, n, bsum, rpE1);
    }
    hipMemcpyAsync(cntE1, rpE1, (size_t)NG * 4, hipMemcpyDeviceToDevice, stream);
    fillE_k<<<(E1_N + 255) / 256, blk, 0, stream>>>(e1_wi, E1_N, cntE1, colE1);

    hipMemsetAsync(cntE2, 0, (size_t)NR * 4, stream);
    histE_k<<<(E2_N + 255) / 256, blk, 0, stream>>>(e2_wi, E2_N, cntE2);
    {
        int n = NR, nb = (n + SCAN_CHUNK - 1) / SCAN_CHUNK;
        scan1_k<<<nb, blk, 0, stream>>>(cntE2, n, bsum);
        scan2_k<<<1, blk, 0, stream>>>(bsum, nb);
        scan3_k<<<nb, blk, 0, stream>>>(cntE2, n, bsum, rpE2);
    }
    hipMemcpyAsync(cntE2, rpE2, (size_t)NR * 4, hipMemcpyDeviceToDevice, stream);
    fillE_k<<<(E2_N + 255) / 256, blk, 0, stream>>>(e2_wi, E2_N, cntE2, colE2);

    // ---------------- lane_pooling #1 (roi -> graph) ----------------
    edgefull_k<float><<<gE32, blk128, 0, stream>>>(
        e1_hi, e1_wi, roi_feat, roi_pose, graph_pose, lp_rpw, lp_rpb,
        wb(0), wb(1), lp_c1gn, hbuf, E1_N);
    lptail_k<false><<<gNG32, blk128, 0, stream>>>(
        hbuf, rpE1, colE1, nullptr, wb(5), nullptr, wb(7), wb(9),
        lp_ngn, lp_m1gn, lp_m2gn, gA, g8A, NG);

    // ---------------- global_graph: 4 fused layers ----------------
    for (int i = 0; i < 4; ++i) {
        FW fw;
        for (int k = 0; k < 12; ++k) fw.w[k] = wb(15 + i * 12 + k);
        fw.w[12] = wb(63 + i); fw.w[13] = wb(67 + i);
        fw.w[14] = wb(11 + i); fw.w[15] = wb(71 + i);
        const __bf16* src = (i & 1) ? gB : gA;
        __bf16* dst = (i & 1) ? gA : gB;
        const unsigned char* src8 = (i & 1) ? g8B : g8A;
        unsigned char* dst8 = (i & 1) ? g8A : g8B;
        fusedlayer_k<<<gNG32, blk128, 0, stream>>>(
            src, src8, rp14, col14, fw, f_ngn + (size_t)i * 256,
            f_c2gn + (size_t)i * 256, dst, dst8, NG);
    }
    // after i=3: result in gA

    // ---------------- lane_pooling #2 (graph -> roi) ----------------
    edgefull_k<__bf16><<<gE32, blk128, 0, stream>>>(
        e2_hi, e2_wi, gA, graph_pose, roi_pose, lp_rpw + 512, lp_rpb + 128,
        wb(2), wb(3), lp_c1gn + 256, hbuf, E2_N);
    lptail_k<true><<<gNR32, blk128, 0, stream>>>(
        hbuf, rpE2, colE2, roi_feat, wb(6), wb(4), wb(8), wb(10),
        lp_ngn + 256, lp_m1gn + 256, lp_m2gn + 256, out, nullptr, NR);
}

// Round 14
// 830.888 us; speedup vs baseline: 1.4664x; 1.4664x over previous
//
#include <hip/hip_runtime.h>

#define NG 50000
#define NR 12000
#define EPS_N 50000
#define ELR_N 5000
#define E1_N 150000
#define E2_N 150000
#define GN_EPS_F 1e-5f
#define SCAN_CHUNK 4096
#define WST 136   // wave-LDS tile row stride (bf16 elems)

typedef __attribute__((ext_vector_type(8))) __bf16 bf16x8;
typedef __attribute__((ext_vector_type(4))) float f32x4;
typedef __attribute__((ext_vector_type(2))) float f32x2;

__device__ __forceinline__ bf16x8 cvt8(const float* __restrict__ p) {
    float4 x0 = *reinterpret_cast<const float4*>(p);
    float4 x1 = *reinterpret_cast<const float4*>(p + 4);
    bf16x8 a;
    a[0] = (__bf16)x0.x; a[1] = (__bf16)x0.y; a[2] = (__bf16)x0.z; a[3] = (__bf16)x0.w;
    a[4] = (__bf16)x1.x; a[5] = (__bf16)x1.y; a[6] = (__bf16)x1.z; a[7] = (__bf16)x1.w;
    return a;
}

// ---------- manual OCP e4m3 quantizer (values are post-relu, >= 0) ----------
__device__ __forceinline__ unsigned f32_to_fp8(float f) {
    f = fminf(f, 448.f);
    unsigned bits = __float_as_uint(f);
    int e = (int)((bits >> 23) & 0xff) - 127;
    if (e < -9) return 0u;
    if (e < -6) {                       // denormal: round(f * 2^9)
        return (unsigned)(int)(f * 512.f + 0.5f);
    }
    unsigned m = (bits >> 20) & 7;
    unsigned r = (bits >> 19) & 1;
    unsigned em = ((unsigned)(e + 7) << 3) | m;
    em += r;
    if (em > 0x7Eu) em = 0x7Eu;        // clamp below NaN (max 448)
    return em;
}

// ====== weight prep: f32 -> fragment-major bf16 (global, coalesced reads) ===
struct PrepTab { const float* src[80]; int stride[80]; int n; };

__global__ void prepw_k(PrepTab tab, __bf16* __restrict__ wbuf)
{
    int t = blockIdx.x * 256 + threadIdx.x;
    int w = t >> 11;
    if (w >= tab.n) return;
    int rr = t & 2047;
    int chunk = rr >> 6, l = rr & 63;
    int wn = chunk >> 4, ks = (chunk >> 2) & 3, ni = chunk & 3;
    int c = wn * 64 + ni * 16 + (l & 15);
    int kb = (ks * 4 + (l >> 4)) * 8;
    const float* s = tab.src[w] + (size_t)c * tab.stride[w] + kb;
    bf16x8 o;
    #pragma unroll
    for (int e = 0; e < 8; ++e) o[e] = (__bf16)s[e];
    *reinterpret_cast<bf16x8*>(wbuf + (size_t)w * 16384 + rr * 8) = o;
}

// ============================ CSR construction =============================
__global__ void hist14_k(const int* __restrict__ ps_u, const int* __restrict__ lr_u,
                         int* __restrict__ cnt)
{
    int t = blockIdx.x * 256 + threadIdx.x;
    const int total = 12 * EPS_N + 2 * ELR_N;
    if (t >= total) return;
    int k, u;
    if (t < 12 * EPS_N) { k = t / EPS_N; u = ps_u[t]; }
    else { int r = t - 12 * EPS_N; k = 12 + r / ELR_N; u = lr_u[r]; }
    atomicAdd(&cnt[k * NG + u], 1);
}

__global__ void fill14_k(const int* __restrict__ ps_u, const int* __restrict__ ps_v,
                         const int* __restrict__ lr_u, const int* __restrict__ lr_v,
                         int* __restrict__ head, int* __restrict__ col)
{
    int t = blockIdx.x * 256 + threadIdx.x;
    const int total = 12 * EPS_N + 2 * ELR_N;
    if (t >= total) return;
    int k, u, v;
    if (t < 12 * EPS_N) { k = t / EPS_N; u = ps_u[t]; v = ps_v[t]; }
    else { int r = t - 12 * EPS_N; k = 12 + r / ELR_N; u = lr_u[r]; v = lr_v[r]; }
    int pos = atomicAdd(&head[k * NG + u], 1);
    col[pos] = v;
}

__global__ void histE_k(const int* __restrict__ wi, int n, int* __restrict__ cnt)
{
    int t = blockIdx.x * 256 + threadIdx.x;
    if (t >= n) return;
    atomicAdd(&cnt[wi[t]], 1);
}

__global__ void fillE_k(const int* __restrict__ wi, int n,
                        int* __restrict__ head, int* __restrict__ col)
{
    int t = blockIdx.x * 256 + threadIdx.x;
    if (t >= n) return;
    int pos = atomicAdd(&head[wi[t]], 1);
    col[pos] = t;
}

__global__ void scan1_k(const int* __restrict__ in, int n, int* __restrict__ bsum)
{
    __shared__ int sm[4];
    int base = blockIdx.x * SCAN_CHUNK;
    int s = 0;
    for (int i = threadIdx.x; i < SCAN_CHUNK; i += 256) {
        int idx = base + i;
        s += (idx < n) ? in[idx] : 0;
    }
    #pragma unroll
    for (int off = 1; off < 64; off <<= 1) s += __shfl_xor(s, off);
    if ((threadIdx.x & 63) == 0) sm[threadIdx.x >> 6] = s;
    __syncthreads();
    if (threadIdx.x == 0) bsum[blockIdx.x] = sm[0] + sm[1] + sm[2] + sm[3];
}

__global__ void scan2_k(int* __restrict__ bsum, int nb)
{
    if (threadIdx.x == 0) {
        int acc = 0;
        for (int i = 0; i < nb; ++i) { int t = bsum[i]; bsum[i] = acc; acc += t; }
    }
}

__global__ void scan3_k(const int* __restrict__ in, int n,
                        const int* __restrict__ bsum, int* __restrict__ outp)
{
    __shared__ int sm[256];
    int base = blockIdx.x * SCAN_CHUNK;
    int loc[16]; int s = 0;
    #pragma unroll
    for (int i = 0; i < 16; ++i) {
        int idx = base + threadIdx.x * 16 + i;
        loc[i] = (idx < n) ? in[idx] : 0; s += loc[i];
    }
    sm[threadIdx.x] = s; __syncthreads();
    for (int off = 1; off < 256; off <<= 1) {
        int v = (threadIdx.x >= off) ? sm[threadIdx.x - off] : 0;
        __syncthreads();
        sm[threadIdx.x] += v;
        __syncthreads();
    }
    int tp = (threadIdx.x ? sm[threadIdx.x - 1] : 0) + bsum[blockIdx.x];
    #pragma unroll
    for (int i = 0; i < 16; ++i) {
        int idx = base + threadIdx.x * 16 + i;
        if (idx < n) outp[idx] = tp;
        tp += loc[i];
        if (idx == n - 1) outp[n] = tp;
    }
}

// ================ wave-autonomous GEMM helpers (BM=16 per wave) =============
__device__ __forceinline__ void mfma16(f32x4 (&acc)[8], const bf16x8 (&a)[4],
                                       const __bf16* __restrict__ gw, int lane)
{
    const __bf16* gwb = gw + lane * 8;
    #pragma unroll
    for (int ks = 0; ks < 4; ++ks) {
        #pragma unroll
        for (int n2 = 0; n2 < 8; ++n2) {
            const int chunk = (n2 >> 2) * 16 + ks * 4 + (n2 & 3);
            bf16x8 b = *reinterpret_cast<const bf16x8*>(gwb + chunk * 512);
            acc[n2] = __builtin_amdgcn_mfma_f32_16x16x32_bf16(a[ks], b, acc[n2], 0, 0, 0);
        }
    }
}

__device__ __forceinline__ void ss_to_frags(const float (&ss)[32], bf16x8 (&a)[4])
{
    #pragma unroll
    for (int ks = 0; ks < 4; ++ks)
        #pragma unroll
        for (int i = 0; i < 8; ++i)
            a[ks][i] = (__bf16)ss[ks * 8 + i];
}

__device__ __forceinline__ void gn_mi(const f32x4 (&acc)[8], float (&m)[4], float (&inv)[4])
{
    #pragma unroll
    for (int reg = 0; reg < 4; ++reg) {
        float s = 0.f, q = 0.f;
        #pragma unroll
        for (int n2 = 0; n2 < 8; ++n2) { float v = acc[n2][reg]; s += v; q = fmaf(v, v, q); }
        #pragma unroll
        for (int off = 1; off < 16; off <<= 1) {
            s += __shfl_xor(s, off);
            q += __shfl_xor(q, off);
        }
        m[reg] = s * (1.f / 128.f);
        inv[reg] = rsqrtf(fmaxf(q * (1.f / 128.f) - m[reg] * m[reg], 0.f) + GN_EPS_F);
    }
}

__device__ __forceinline__ void gn_relayout(const f32x4 (&acc)[8], const float* __restrict__ sb,
                                            __bf16* wl, bf16x8 (&a)[4], int r16, int kq)
{
    float m[4], inv[4];
    gn_mi(acc, m, inv);
    #pragma unroll
    for (int reg = 0; reg < 4; ++reg) {
        #pragma unroll
        for (int n2 = 0; n2 < 8; ++n2) {
            const int colc = n2 * 16 + r16;
            float y = (acc[n2][reg] - m[reg]) * inv[reg] * sb[colc] + sb[128 + colc];
            wl[(kq * 4 + reg) * WST + colc] = (__bf16)fmaxf(y, 0.f);
        }
    }
    #pragma unroll
    for (int ks = 0; ks < 4; ++ks)
        a[ks] = *reinterpret_cast<const bf16x8*>(wl + r16 * WST + ks * 32 + kq * 8);
}

// ============ edgefull: h[e] = relu(gn(ctx[hi]@c1A + dist@c1B, sb)) =========
template<typename CT>
__launch_bounds__(128, 3)
__global__ void edgefull_k(const int* __restrict__ hi_idx, const int* __restrict__ wi_idx,
                           const CT* __restrict__ ctxfeat,
                           const float* __restrict__ cpose, const float* __restrict__ tpose,
                           const float* __restrict__ rpw, const float* __restrict__ rpb,
                           const __bf16* __restrict__ wc1A, const __bf16* __restrict__ wc1B,
                           const float* __restrict__ sb,
                           __bf16* __restrict__ hout, int M)
{
    __shared__ float rw[640];
    const int tid = threadIdx.x, lane = tid & 63, wv = tid >> 6;
    const int r16 = lane & 15, kq = lane >> 4;
    const int wbase = blockIdx.x * 32 + wv * 16;
    const int erow = wbase + r16;
    const int ec = erow < M ? erow : M - 1;

    for (int i = tid; i < 640; i += 128)
        rw[i] = (i < 512) ? rpw[i] : rpb[i - 512];
    __syncthreads();

    const int hi = hi_idx[ec], wi = wi_idx[ec];
    float4 cp = *reinterpret_cast<const float4*>(cpose + (size_t)hi * 4);
    float4 tp = *reinterpret_cast<const float4*>(tpose + (size_t)wi * 4);
    const float d0 = cp.x - tp.x, d1 = cp.y - tp.y, d2 = cp.z - tp.z, d3 = cp.w - tp.w;

    f32x4 acc[8];
    #pragma unroll
    for (int n2 = 0; n2 < 8; ++n2) acc[n2] = (f32x4){0.f, 0.f, 0.f, 0.f};

    {   // ctx[hi] @ c1A
        bf16x8 a[4];
        const CT* sp = ctxfeat + (size_t)hi * 128 + kq * 8;
        #pragma unroll
        for (int ks = 0; ks < 4; ++ks) {
            if constexpr (sizeof(CT) == 4) a[ks] = cvt8((const float*)sp + ks * 32);
            else a[ks] = *reinterpret_cast<const bf16x8*>((const __bf16*)sp + ks * 32);
        }
        mfma16(acc, a, wc1A, lane);
    }
    {   // dist @ c1B (A built in-register)
        bf16x8 a[4];
        #pragma unroll
        for (int ks = 0; ks < 4; ++ks)
            #pragma unroll
            for (int i = 0; i < 8; ++i) {
                const int k = ks * 32 + kq * 8 + i;
                float4 w4 = *reinterpret_cast<const float4*>(&rw[k * 4]);
                float d = fmaf(d0, w4.x, fmaf(d1, w4.y, fmaf(d2, w4.z,
                          fmaf(d3, w4.w, rw[512 + k]))));
                a[ks][i] = (__bf16)fmaxf(d, 0.f);
            }
        mfma16(acc, a, wc1B, lane);
    }

    float m[4], inv[4];
    gn_mi(acc, m, inv);
    #pragma unroll
    for (int reg = 0; reg < 4; ++reg) {
        const int crow = wbase + kq * 4 + reg;
        if (crow < M) {
            __bf16* dp = hout + (size_t)crow * 128 + r16;
            #pragma unroll
            for (int n2 = 0; n2 < 8; ++n2) {
                const int colc = n2 * 16 + r16;
                float y = (acc[n2][reg] - m[reg]) * inv[reg] * sb[colc] + sb[128 + colc];
                dp[n2 * 16] = (__bf16)fmaxf(y, 0.f);
            }
        }
    }
}

// ======= fusedlayer: fp8 gathers decoded with HW v_cvt_pk_f32_fp8 ==========
struct FW { const __bf16* w[16]; };   // 0..11 ps, 12 left, 13 right, 14 ctr, 15 ctr2

__launch_bounds__(128, 3)
__global__ void fusedlayer_k(const __bf16* __restrict__ feat,
                             const unsigned char* __restrict__ feat8,
                             const int* __restrict__ rp, const int* __restrict__ col,
                             FW fw, const float* __restrict__ gn1,
                             const float* __restrict__ gn2,
                             __bf16* __restrict__ outp,
                             unsigned char* __restrict__ out8, int M)
{
    __shared__ __bf16 wl[2][16 * WST];
    const int tid = threadIdx.x, lane = tid & 63, wv = tid >> 6;
    const int r16 = lane & 15, kq = lane >> 4;
    const int wbase = blockIdx.x * 32 + wv * 16;
    const int wrow = (wbase + r16) < M ? (wbase + r16) : M - 1;

    // prefetch all CSR extents (28 independent loads) + first col per scale
    int beg[14], deg[14], c0[14];
    #pragma unroll
    for (int j = 0; j < 14; ++j) {
        beg[j] = rp[j * M + wrow];
        deg[j] = rp[j * M + wrow + 1] - beg[j];
    }
    #pragma unroll
    for (int j = 0; j < 14; ++j)
        c0[j] = col[deg[j] > 0 ? beg[j] : 0];   // in-bounds; zeroed via flag

    f32x4 acc[8];
    #pragma unroll
    for (int n2 = 0; n2 < 8; ++n2) acc[n2] = (f32x4){0.f, 0.f, 0.f, 0.f};

    #pragma unroll
    for (int j = 0; j < 15; ++j) {
        float ss[32];
        if (j == 14) {
            const __bf16* sp = feat + (size_t)wrow * 128 + kq * 8;
            #pragma unroll
            for (int ks = 0; ks < 4; ++ks) {
                bf16x8 h = *reinterpret_cast<const bf16x8*>(sp + ks * 32);
                #pragma unroll
                for (int i = 0; i < 8; ++i) ss[ks * 8 + i] = (float)h[i];
            }
        } else {
            const float f0 = deg[j] > 0 ? 1.f : 0.f;
            {   // base row (index prefetched, flag-weighted)
                const unsigned char* sp = feat8 + (size_t)c0[j] * 128 + kq * 8;
                #pragma unroll
                for (int ks = 0; ks < 4; ++ks) {
                    uint2 u = *reinterpret_cast<const uint2*>(sp + ks * 32);
                    f32x2 v0 = __builtin_amdgcn_cvt_pk_f32_fp8(u.x, false);
                    f32x2 v1 = __builtin_amdgcn_cvt_pk_f32_fp8(u.x, true);
                    f32x2 v2 = __builtin_amdgcn_cvt_pk_f32_fp8(u.y, false);
                    f32x2 v3 = __builtin_amdgcn_cvt_pk_f32_fp8(u.y, true);
                    ss[ks*8+0] = f0 * v0[0]; ss[ks*8+1] = f0 * v0[1];
                    ss[ks*8+2] = f0 * v1[0]; ss[ks*8+3] = f0 * v1[1];
                    ss[ks*8+4] = f0 * v2[0]; ss[ks*8+5] = f0 * v2[1];
                    ss[ks*8+6] = f0 * v3[0]; ss[ks*8+7] = f0 * v3[1];
                }
            }
            // rare tail deg >= 2
            for (int t2 = beg[j] + 1; t2 < beg[j] + deg[j]; ++t2) {
                const unsigned char* sp = feat8 + (size_t)col[t2] * 128 + kq * 8;
                #pragma unroll
                for (int ks = 0; ks < 4; ++ks) {
                    uint2 u = *reinterpret_cast<const uint2*>(sp + ks * 32);
                    f32x2 v0 = __builtin_amdgcn_cvt_pk_f32_fp8(u.x, false);
                    f32x2 v1 = __builtin_amdgcn_cvt_pk_f32_fp8(u.x, true);
                    f32x2 v2 = __builtin_amdgcn_cvt_pk_f32_fp8(u.y, false);
                    f32x2 v3 = __builtin_amdgcn_cvt_pk_f32_fp8(u.y, true);
                    ss[ks*8+0] += v0[0]; ss[ks*8+1] += v0[1];
                    ss[ks*8+2] += v1[0]; ss[ks*8+3] += v1[1];
                    ss[ks*8+4] += v2[0]; ss[ks*8+5] += v2[1];
                    ss[ks*8+6] += v3[0]; ss[ks*8+7] += v3[1];
                }
            }
        }
        bf16x8 a[4];
        ss_to_frags(ss, a);
        mfma16(acc, a, fw.w[j], lane);
    }

    // GN1 + relu -> wave LDS -> A-frags; ctr2 GEMM
    bf16x8 a2[4];
    gn_relayout(acc, gn1, wl[wv], a2, r16, kq);
    f32x4 acc2[8];
    #pragma unroll
    for (int n2 = 0; n2 < 8; ++n2) acc2[n2] = (f32x4){0.f, 0.f, 0.f, 0.f};
    mfma16(acc2, a2, fw.w[15], lane);

    // GN2 + residual + relu -> out (bf16 + fp8 shadow)
    float m[4], inv[4];
    gn_mi(acc2, m, inv);
    #pragma unroll
    for (int reg = 0; reg < 4; ++reg) {
        const int crow = wbase + kq * 4 + reg;
        if (crow < M) {
            __bf16* dp = outp + (size_t)crow * 128 + r16;
            unsigned char* d8 = out8 + (size_t)crow * 128 + r16;
            const __bf16* rs = feat + (size_t)crow * 128 + r16;
            #pragma unroll
            for (int n2 = 0; n2 < 8; ++n2) {
                const int colc = n2 * 16 + r16;
                float y = (acc2[n2][reg] - m[reg]) * inv[reg] * gn2[colc] + gn2[128 + colc];
                y += (float)rs[n2 * 16];
                y = fmaxf(y, 0.f);
                dp[n2 * 16] = (__bf16)y;
                d8[n2 * 16] = (unsigned char)f32_to_fp8(y);
            }
        }
    }
}

// ============= lptail: lane_pooling tail (R9 + optional fp8 shadow) =========
template<bool LP2>
__launch_bounds__(128, 3)
__global__ void lptail_k(const __bf16* __restrict__ hsrc,
                         const int* __restrict__ rp, const int* __restrict__ col,
                         const float* __restrict__ roi,
                         const __bf16* __restrict__ wc2, const __bf16* __restrict__ winW,
                         const __bf16* __restrict__ wm1, const __bf16* __restrict__ wm2,
                         const float* __restrict__ ngn, const float* __restrict__ m1gn,
                         const float* __restrict__ m2gn,
                         void* __restrict__ outp,
                         unsigned char* __restrict__ out8, int M)
{
    __shared__ __bf16 wl[2][16 * WST];
    const int tid = threadIdx.x, lane = tid & 63, wv = tid >> 6;
    const int r16 = lane & 15, kq = lane >> 4;
    const int wbase = blockIdx.x * 32 + wv * 16;
    const int wrow = (wbase + r16) < M ? (wbase + r16) : M - 1;

    f32x4 acc[8];
    #pragma unroll
    for (int n2 = 0; n2 < 8; ++n2) acc[n2] = (f32x4){0.f, 0.f, 0.f, 0.f};

    {   // (Σ h) @ c2
        float ss[32];
        #pragma unroll
        for (int i = 0; i < 32; ++i) ss[i] = 0.f;
        const int b = rp[wrow], e = rp[wrow + 1];
        for (int t2 = b; t2 < e; ++t2) {
            const __bf16* sp = hsrc + (size_t)col[t2] * 128 + kq * 8;
            #pragma unroll
            for (int ks = 0; ks < 4; ++ks) {
                bf16x8 h = *reinterpret_cast<const bf16x8*>(sp + ks * 32);
                #pragma unroll
                for (int i = 0; i < 8; ++i) ss[ks * 8 + i] += (float)h[i];
            }
        }
        bf16x8 a[4];
        ss_to_frags(ss, a);
        mfma16(acc, a, wc2, lane);
    }
    if (LP2) {   // + roi @ input_w
        bf16x8 a[4];
        const float* sp = roi + (size_t)wrow * 128 + kq * 8;
        #pragma unroll
        for (int ks = 0; ks < 4; ++ks) a[ks] = cvt8(sp + ks * 32);
        mfma16(acc, a, winW, lane);
    }

    {   // relu(gn(.,ngn)) @ m1
        bf16x8 a[4];
        gn_relayout(acc, ngn, wl[wv], a, r16, kq);
        #pragma unroll
        for (int n2 = 0; n2 < 8; ++n2) acc[n2] = (f32x4){0.f, 0.f, 0.f, 0.f};
        mfma16(acc, a, wm1, lane);
    }
    {   // relu(gn(.,m1gn)) @ m2
        bf16x8 a[4];
        gn_relayout(acc, m1gn, wl[wv], a, r16, kq);
        #pragma unroll
        for (int n2 = 0; n2 < 8; ++n2) acc[n2] = (f32x4){0.f, 0.f, 0.f, 0.f};
        mfma16(acc, a, wm2, lane);
    }

    float m[4], inv[4];
    gn_mi(acc, m, inv);
    #pragma unroll
    for (int reg = 0; reg < 4; ++reg) {
        const int crow = wbase + kq * 4 + reg;
        if (crow < M) {
            #pragma unroll
            for (int n2 = 0; n2 < 8; ++n2) {
                const int colc = n2 * 16 + r16;
                float y = (acc[n2][reg] - m[reg]) * inv[reg] * m2gn[colc] + m2gn[128 + colc];
                if (LP2) {
                    y += roi[(size_t)crow * 128 + colc];
                    ((float*)outp)[(size_t)crow * 128 + colc] = fmaxf(y, 0.f);
                } else {
                    y = fmaxf(y, 0.f);
                    ((__bf16*)outp)[(size_t)crow * 128 + colc] = (__bf16)y;
                    out8[(size_t)crow * 128 + colc] = (unsigned char)f32_to_fp8(y);
                }
            }
        }
    }
}

// ===========================================================================
extern "C" void kernel_launch(void* const* d_in, const int* in_sizes, int n_in,
                              void* d_out, int out_size, void* d_ws, size_t ws_size,
                              hipStream_t stream)
{
    const float* roi_feat   = (const float*)d_in[0];
    const float* graph_pose = (const float*)d_in[1];
    const float* roi_pose   = (const float*)d_in[2];
    const float* lp_input_w = (const float*)d_in[3];
    const float* lp_rpw     = (const float*)d_in[4];
    const float* lp_rpb     = (const float*)d_in[5];
    const float* lp_c1w     = (const float*)d_in[6];
    const float* lp_c1gn    = (const float*)d_in[7];
    const float* lp_c2w     = (const float*)d_in[8];
    const float* lp_m1w     = (const float*)d_in[9];
    const float* lp_m1gn    = (const float*)d_in[10];
    const float* lp_m2w     = (const float*)d_in[11];
    const float* lp_m2gn    = (const float*)d_in[12];
    const float* lp_ngn     = (const float*)d_in[13];
    const float* f_ctrw     = (const float*)d_in[14];
    const float* f_psw      = (const float*)d_in[15];
    const float* f_lw       = (const float*)d_in[16];
    const float* f_rw       = (const float*)d_in[17];
    const float* f_ngn      = (const float*)d_in[18];
    const float* f_c2w      = (const float*)d_in[19];
    const float* f_c2gn     = (const float*)d_in[20];
    const int* e1_hi = (const int*)d_in[21];
    const int* e1_wi = (const int*)d_in[22];
    const int* e2_hi = (const int*)d_in[23];
    const int* e2_wi = (const int*)d_in[24];
    const int* ps_u  = (const int*)d_in[25];
    const int* ps_v  = (const int*)d_in[26];
    const int* lr_u  = (const int*)d_in[27];
    const int* lr_v  = (const int*)d_in[28];
    float* out = (float*)d_out;

    // ---- workspace (~90 MB) ----
    __bf16* gA   = (__bf16*)d_ws;                       // NG*128
    __bf16* gB   = gA + (size_t)NG * 128;               // NG*128
    __bf16* hbuf = gB + (size_t)NG * 128;               // E1_N*128
    __bf16* wbuf = hbuf + (size_t)E1_N * 128;           // 80*16384
    unsigned char* g8A = (unsigned char*)(wbuf + (size_t)80 * 16384); // NG*128 B
    unsigned char* g8B = g8A + (size_t)NG * 128;                      // NG*128 B
    int* ip      = (int*)(g8B + (size_t)NG * 128);
    int* cnt14   = ip;             ip += 14 * NG;
    int* rp14    = ip;             ip += 14 * NG + 1;
    int* col14   = ip;             ip += 12 * EPS_N + 2 * ELR_N;
    int* cntE1   = ip;             ip += NG;
    int* rpE1    = ip;             ip += NG + 1;
    int* colE1   = ip;             ip += E1_N;
    int* cntE2   = ip;             ip += NR;
    int* rpE2    = ip;             ip += NR + 1;
    int* colE2   = ip;             ip += E2_N;
    int* bsum    = ip;             ip += 256;

    dim3 blk(256), blk128(128);
    const dim3 gNG32((NG + 31) / 32), gNR32((NR + 31) / 32), gE32((E1_N + 31) / 32);
    const int NE14 = 12 * EPS_N + 2 * ELR_N;
    const dim3 gH14((NE14 + 255) / 256);

    // ---------------- weight prep ----------------
    PrepTab tab; int nw = 0;
    auto addw = [&](const float* p, int s) { tab.src[nw] = p; tab.stride[nw] = s; ++nw; };
    addw(lp_c1w, 256);                 // 0 c1A_0
    addw(lp_c1w + 128, 256);           // 1 c1B_0
    addw(lp_c1w + 32768, 256);         // 2 c1A_1
    addw(lp_c1w + 32768 + 128, 256);   // 3 c1B_1
    addw(lp_input_w + 16384, 128);     // 4 input_w[1]
    addw(lp_c2w, 128); addw(lp_c2w + 16384, 128);   // 5,6
    addw(lp_m1w, 128); addw(lp_m1w + 16384, 128);   // 7,8
    addw(lp_m2w, 128); addw(lp_m2w + 16384, 128);   // 9,10
    for (int i = 0; i < 4; ++i) addw(f_ctrw + (size_t)i * 16384, 128);      // 11..14
    for (int i = 0; i < 4; ++i)
        for (int k = 0; k < 12; ++k) addw(f_psw + ((size_t)i * 12 + k) * 16384, 128);
    for (int i = 0; i < 4; ++i) addw(f_lw + (size_t)i * 16384, 128);        // 63..66
    for (int i = 0; i < 4; ++i) addw(f_rw + (size_t)i * 16384, 128);        // 67..70
    for (int i = 0; i < 4; ++i) addw(f_c2w + (size_t)i * 16384, 128);       // 71..74
    tab.n = nw;
    auto wb = [&](int idx) { return (const __bf16*)(wbuf + (size_t)idx * 16384); };
    prepw_k<<<dim3((nw * 2048 + 255) / 256), blk, 0, stream>>>(tab, wbuf);

    // ---------------- CSR builds ----------------
    hipMemsetAsync(cnt14, 0, (size_t)14 * NG * 4, stream);
    hist14_k<<<gH14, blk, 0, stream>>>(ps_u, lr_u, cnt14);
    {
        int n = 14 * NG, nb = (n + SCAN_CHUNK - 1) / SCAN_CHUNK;
        scan1_k<<<nb, blk, 0, stream>>>(cnt14, n, bsum);
        scan2_k<<<1, blk, 0, stream>>>(bsum, nb);
        scan3_k<<<nb, blk, 0, stream>>>(cnt14, n, bsum, rp14);
    }
    hipMemcpyAsync(cnt14, rp14, (size_t)14 * NG * 4, hipMemcpyDeviceToDevice, stream);
    fill14_k<<<gH14, blk, 0, stream>>>(ps_u, ps_v, lr_u, lr_v, cnt14, col14);

    hipMemsetAsync(cntE1, 0, (size_t)NG * 4, stream);
    histE_k<<<(E1_N + 255) / 256, blk, 0, stream>>>(e1_wi, E1_N, cntE1);
    {
        int n = NG, nb = (n + SCAN_CHUNK - 1) / SCAN_CHUNK;
        scan1_k<<<nb, blk, 0, stream>>>(cntE1, n, bsum);
        scan2_k<<<1, blk, 0, stream>>>(bsum, nb);
        scan3_k<<<nb, blk, 0, stream>>>(cntE1, n, bsum, rpE1);
    }
    hipMemcpyAsync(cntE1, rpE1, (size_t)NG * 4, hipMemcpyDeviceToDevice, stream);
    fillE_k<<<(E1_N + 255) / 256, blk, 0, stream>>>(e1_wi, E1_N, cntE1, colE1);

    hipMemsetAsync(cntE2, 0, (size_t)NR * 4, stream);
    histE_k<<<(E2_N + 255) / 256, blk, 0, stream>>>(e2_wi, E2_N, cntE2);
    {
        int n = NR, nb = (n + SCAN_CHUNK - 1) / SCAN_CHUNK;
        scan1_k<<<nb, blk, 0, stream>>>(cntE2, n, bsum);
        scan2_k<<<1, blk, 0, stream>>>(bsum, nb);
        scan3_k<<<nb, blk, 0, stream>>>(cntE2, n, bsum, rpE2);
    }
    hipMemcpyAsync(cntE2, rpE2, (size_t)NR * 4, hipMemcpyDeviceToDevice, stream);
    fillE_k<<<(E2_N + 255) / 256, blk, 0, stream>>>(e2_wi, E2_N, cntE2, colE2);

    // ---------------- lane_pooling #1 (roi -> graph) ----------------
    edgefull_k<float><<<gE32, blk128, 0, stream>>>(
        e1_hi, e1_wi, roi_feat, roi_pose, graph_pose, lp_rpw, lp_rpb,
        wb(0), wb(1), lp_c1gn, hbuf, E1_N);
    lptail_k<false><<<gNG32, blk128, 0, stream>>>(
        hbuf, rpE1, colE1, nullptr, wb(5), nullptr, wb(7), wb(9),
        lp_ngn, lp_m1gn, lp_m2gn, gA, g8A, NG);

    // ---------------- global_graph: 4 fused layers ----------------
    for (int i = 0; i < 4; ++i) {
        FW fw;
        for (int k = 0; k < 12; ++k) fw.w[k] = wb(15 + i * 12 + k);
        fw.w[12] = wb(63 + i); fw.w[13] = wb(67 + i);
        fw.w[14] = wb(11 + i); fw.w[15] = wb(71 + i);
        const __bf16* src = (i & 1) ? gB : gA;
        __bf16* dst = (i & 1) ? gA : gB;
        const unsigned char* src8 = (i & 1) ? g8B : g8A;
        unsigned char* dst8 = (i & 1) ? g8A : g8B;
        fusedlayer_k<<<gNG32, blk128, 0, stream>>>(
            src, src8, rp14, col14, fw, f_ngn + (size_t)i * 256,
            f_c2gn + (size_t)i * 256, dst, dst8, NG);
    }
    // after i=3: result in gA

    // ---------------- lane_pooling #2 (graph -> roi) ----------------
    edgefull_k<__bf16><<<gE32, blk128, 0, stream>>>(
        e2_hi, e2_wi, gA, graph_pose, roi_pose, lp_rpw + 512, lp_rpb + 128,
        wb(2), wb(3), lp_c1gn + 256, hbuf, E2_N);
    lptail_k<true><<<gNR32, blk128, 0, stream>>>(
        hbuf, rpE2, colE2, roi_feat, wb(6), wb(4), wb(8), wb(10),
        lp_ngn + 256, lp_m1gn + 256, lp_m2gn + 256, out, nullptr, NR);
}

// Round 15
// 699.363 us; speedup vs baseline: 1.7422x; 1.1881x over previous
//
#include <hip/hip_runtime.h>

#define NG 50000
#define NR 12000
#define EPS_N 50000
#define ELR_N 5000
#define E1_N 150000
#define E2_N 150000
#define GN_EPS_F 1e-5f
#define SCAN_CHUNK 4096
#define WST 136    // wave-LDS tile row stride (bf16 elems)
#define SST 176    // fp8 staging row stride (bytes, 16B-aligned, conflict-light)

typedef __attribute__((ext_vector_type(8))) __bf16 bf16x8;
typedef __attribute__((ext_vector_type(4))) float f32x4;
typedef __attribute__((ext_vector_type(2))) float f32x2;

__device__ __forceinline__ bf16x8 cvt8(const float* __restrict__ p) {
    float4 x0 = *reinterpret_cast<const float4*>(p);
    float4 x1 = *reinterpret_cast<const float4*>(p + 4);
    bf16x8 a;
    a[0] = (__bf16)x0.x; a[1] = (__bf16)x0.y; a[2] = (__bf16)x0.z; a[3] = (__bf16)x0.w;
    a[4] = (__bf16)x1.x; a[5] = (__bf16)x1.y; a[6] = (__bf16)x1.z; a[7] = (__bf16)x1.w;
    return a;
}

// ---------- manual OCP e4m3 quantizer (values are post-relu, >= 0) ----------
__device__ __forceinline__ unsigned f32_to_fp8(float f) {
    f = fminf(f, 448.f);
    unsigned bits = __float_as_uint(f);
    int e = (int)((bits >> 23) & 0xff) - 127;
    if (e < -9) return 0u;
    if (e < -6) {                       // denormal: round(f * 2^9)
        return (unsigned)(int)(f * 512.f + 0.5f);
    }
    unsigned m = (bits >> 20) & 7;
    unsigned r = (bits >> 19) & 1;
    unsigned em = ((unsigned)(e + 7) << 3) | m;
    em += r;
    if (em > 0x7Eu) em = 0x7Eu;        // clamp below NaN (max 448)
    return em;
}

// ====== weight prep: f32 -> fragment-major bf16 (global, coalesced reads) ===
struct PrepTab { const float* src[80]; int stride[80]; int n; };

__global__ void prepw_k(PrepTab tab, __bf16* __restrict__ wbuf)
{
    int t = blockIdx.x * 256 + threadIdx.x;
    int w = t >> 11;
    if (w >= tab.n) return;
    int rr = t & 2047;
    int chunk = rr >> 6, l = rr & 63;
    int wn = chunk >> 4, ks = (chunk >> 2) & 3, ni = chunk & 3;
    int c = wn * 64 + ni * 16 + (l & 15);
    int kb = (ks * 4 + (l >> 4)) * 8;
    const float* s = tab.src[w] + (size_t)c * tab.stride[w] + kb;
    bf16x8 o;
    #pragma unroll
    for (int e = 0; e < 8; ++e) o[e] = (__bf16)s[e];
    *reinterpret_cast<bf16x8*>(wbuf + (size_t)w * 16384 + rr * 8) = o;
}

// ============================ CSR construction =============================
__global__ void hist14_k(const int* __restrict__ ps_u, const int* __restrict__ lr_u,
                         int* __restrict__ cnt)
{
    int t = blockIdx.x * 256 + threadIdx.x;
    const int total = 12 * EPS_N + 2 * ELR_N;
    if (t >= total) return;
    int k, u;
    if (t < 12 * EPS_N) { k = t / EPS_N; u = ps_u[t]; }
    else { int r = t - 12 * EPS_N; k = 12 + r / ELR_N; u = lr_u[r]; }
    atomicAdd(&cnt[k * NG + u], 1);
}

__global__ void fill14_k(const int* __restrict__ ps_u, const int* __restrict__ ps_v,
                         const int* __restrict__ lr_u, const int* __restrict__ lr_v,
                         int* __restrict__ head, int* __restrict__ col)
{
    int t = blockIdx.x * 256 + threadIdx.x;
    const int total = 12 * EPS_N + 2 * ELR_N;
    if (t >= total) return;
    int k, u, v;
    if (t < 12 * EPS_N) { k = t / EPS_N; u = ps_u[t]; v = ps_v[t]; }
    else { int r = t - 12 * EPS_N; k = 12 + r / ELR_N; u = lr_u[r]; v = lr_v[r]; }
    int pos = atomicAdd(&head[k * NG + u], 1);
    col[pos] = v;
}

__global__ void histE_k(const int* __restrict__ wi, int n, int* __restrict__ cnt)
{
    int t = blockIdx.x * 256 + threadIdx.x;
    if (t >= n) return;
    atomicAdd(&cnt[wi[t]], 1);
}

__global__ void fillE_k(const int* __restrict__ wi, int n,
                        int* __restrict__ head, int* __restrict__ col)
{
    int t = blockIdx.x * 256 + threadIdx.x;
    if (t >= n) return;
    int pos = atomicAdd(&head[wi[t]], 1);
    col[pos] = t;
}

__global__ void scan1_k(const int* __restrict__ in, int n, int* __restrict__ bsum)
{
    __shared__ int sm[4];
    int base = blockIdx.x * SCAN_CHUNK;
    int s = 0;
    for (int i = threadIdx.x; i < SCAN_CHUNK; i += 256) {
        int idx = base + i;
        s += (idx < n) ? in[idx] : 0;
    }
    #pragma unroll
    for (int off = 1; off < 64; off <<= 1) s += __shfl_xor(s, off);
    if ((threadIdx.x & 63) == 0) sm[threadIdx.x >> 6] = s;
    __syncthreads();
    if (threadIdx.x == 0) bsum[blockIdx.x] = sm[0] + sm[1] + sm[2] + sm[3];
}

__global__ void scan2_k(int* __restrict__ bsum, int nb)
{
    if (threadIdx.x == 0) {
        int acc = 0;
        for (int i = 0; i < nb; ++i) { int t = bsum[i]; bsum[i] = acc; acc += t; }
    }
}

__global__ void scan3_k(const int* __restrict__ in, int n,
                        const int* __restrict__ bsum, int* __restrict__ outp)
{
    __shared__ int sm[256];
    int base = blockIdx.x * SCAN_CHUNK;
    int loc[16]; int s = 0;
    #pragma unroll
    for (int i = 0; i < 16; ++i) {
        int idx = base + threadIdx.x * 16 + i;
        loc[i] = (idx < n) ? in[idx] : 0; s += loc[i];
    }
    sm[threadIdx.x] = s; __syncthreads();
    for (int off = 1; off < 256; off <<= 1) {
        int v = (threadIdx.x >= off) ? sm[threadIdx.x - off] : 0;
        __syncthreads();
        sm[threadIdx.x] += v;
        __syncthreads();
    }
    int tp = (threadIdx.x ? sm[threadIdx.x - 1] : 0) + bsum[blockIdx.x];
    #pragma unroll
    for (int i = 0; i < 16; ++i) {
        int idx = base + threadIdx.x * 16 + i;
        if (idx < n) outp[idx] = tp;
        tp += loc[i];
        if (idx == n - 1) outp[n] = tp;
    }
}

// ================ wave-autonomous GEMM helpers (BM=16 per wave) =============
__device__ __forceinline__ void mfma16(f32x4 (&acc)[8], const bf16x8 (&a)[4],
                                       const __bf16* __restrict__ gw, int lane)
{
    const __bf16* gwb = gw + lane * 8;
    #pragma unroll
    for (int ks = 0; ks < 4; ++ks) {
        #pragma unroll
        for (int n2 = 0; n2 < 8; ++n2) {
            const int chunk = (n2 >> 2) * 16 + ks * 4 + (n2 & 3);
            bf16x8 b = *reinterpret_cast<const bf16x8*>(gwb + chunk * 512);
            acc[n2] = __builtin_amdgcn_mfma_f32_16x16x32_bf16(a[ks], b, acc[n2], 0, 0, 0);
        }
    }
}

__device__ __forceinline__ void ss_to_frags(const float (&ss)[32], bf16x8 (&a)[4])
{
    #pragma unroll
    for (int ks = 0; ks < 4; ++ks)
        #pragma unroll
        for (int i = 0; i < 8; ++i)
            a[ks][i] = (__bf16)ss[ks * 8 + i];
}

__device__ __forceinline__ void gn_mi(const f32x4 (&acc)[8], float (&m)[4], float (&inv)[4])
{
    #pragma unroll
    for (int reg = 0; reg < 4; ++reg) {
        float s = 0.f, q = 0.f;
        #pragma unroll
        for (int n2 = 0; n2 < 8; ++n2) { float v = acc[n2][reg]; s += v; q = fmaf(v, v, q); }
        #pragma unroll
        for (int off = 1; off < 16; off <<= 1) {
            s += __shfl_xor(s, off);
            q += __shfl_xor(q, off);
        }
        m[reg] = s * (1.f / 128.f);
        inv[reg] = rsqrtf(fmaxf(q * (1.f / 128.f) - m[reg] * m[reg], 0.f) + GN_EPS_F);
    }
}

__device__ __forceinline__ void gn_relayout(const f32x4 (&acc)[8], const float* __restrict__ sb,
                                            __bf16* wl, bf16x8 (&a)[4], int r16, int kq)
{
    float m[4], inv[4];
    gn_mi(acc, m, inv);
    #pragma unroll
    for (int reg = 0; reg < 4; ++reg) {
        #pragma unroll
        for (int n2 = 0; n2 < 8; ++n2) {
            const int colc = n2 * 16 + r16;
            float y = (acc[n2][reg] - m[reg]) * inv[reg] * sb[colc] + sb[128 + colc];
            wl[(kq * 4 + reg) * WST + colc] = (__bf16)fmaxf(y, 0.f);
        }
    }
    #pragma unroll
    for (int ks = 0; ks < 4; ++ks)
        a[ks] = *reinterpret_cast<const bf16x8*>(wl + r16 * WST + ks * 32 + kq * 8);
}

// ============ edgefull: h[e] = relu(gn(ctx[hi]@c1A + dist@c1B, sb)) =========
template<typename CT>
__launch_bounds__(128, 3)
__global__ void edgefull_k(const int* __restrict__ hi_idx, const int* __restrict__ wi_idx,
                           const CT* __restrict__ ctxfeat,
                           const float* __restrict__ cpose, const float* __restrict__ tpose,
                           const float* __restrict__ rpw, const float* __restrict__ rpb,
                           const __bf16* __restrict__ wc1A, const __bf16* __restrict__ wc1B,
                           const float* __restrict__ sb,
                           __bf16* __restrict__ hout, int M)
{
    __shared__ float rw[640];
    const int tid = threadIdx.x, lane = tid & 63, wv = tid >> 6;
    const int r16 = lane & 15, kq = lane >> 4;
    const int wbase = blockIdx.x * 32 + wv * 16;
    const int erow = wbase + r16;
    const int ec = erow < M ? erow : M - 1;

    for (int i = tid; i < 640; i += 128)
        rw[i] = (i < 512) ? rpw[i] : rpb[i - 512];
    __syncthreads();

    const int hi = hi_idx[ec], wi = wi_idx[ec];
    float4 cp = *reinterpret_cast<const float4*>(cpose + (size_t)hi * 4);
    float4 tp = *reinterpret_cast<const float4*>(tpose + (size_t)wi * 4);
    const float d0 = cp.x - tp.x, d1 = cp.y - tp.y, d2 = cp.z - tp.z, d3 = cp.w - tp.w;

    f32x4 acc[8];
    #pragma unroll
    for (int n2 = 0; n2 < 8; ++n2) acc[n2] = (f32x4){0.f, 0.f, 0.f, 0.f};

    {   // ctx[hi] @ c1A
        bf16x8 a[4];
        const CT* sp = ctxfeat + (size_t)hi * 128 + kq * 8;
        #pragma unroll
        for (int ks = 0; ks < 4; ++ks) {
            if constexpr (sizeof(CT) == 4) a[ks] = cvt8((const float*)sp + ks * 32);
            else a[ks] = *reinterpret_cast<const bf16x8*>((const __bf16*)sp + ks * 32);
        }
        mfma16(acc, a, wc1A, lane);
    }
    {   // dist @ c1B (A built in-register)
        bf16x8 a[4];
        #pragma unroll
        for (int ks = 0; ks < 4; ++ks)
            #pragma unroll
            for (int i = 0; i < 8; ++i) {
                const int k = ks * 32 + kq * 8 + i;
                float4 w4 = *reinterpret_cast<const float4*>(&rw[k * 4]);
                float d = fmaf(d0, w4.x, fmaf(d1, w4.y, fmaf(d2, w4.z,
                          fmaf(d3, w4.w, rw[512 + k]))));
                a[ks][i] = (__bf16)fmaxf(d, 0.f);
            }
        mfma16(acc, a, wc1B, lane);
    }

    float m[4], inv[4];
    gn_mi(acc, m, inv);
    #pragma unroll
    for (int reg = 0; reg < 4; ++reg) {
        const int crow = wbase + kq * 4 + reg;
        if (crow < M) {
            __bf16* dp = hout + (size_t)crow * 128 + r16;
            #pragma unroll
            for (int n2 = 0; n2 < 8; ++n2) {
                const int colc = n2 * 16 + r16;
                float y = (acc[n2][reg] - m[reg]) * inv[reg] * sb[colc] + sb[128 + colc];
                dp[n2 * 16] = (__bf16)fmaxf(y, 0.f);
            }
        }
    }
}

// ======= fusedlayer: fp8 gathers, 2x16B coalesced row loads + LDS bounce ====
struct FW { const __bf16* w[16]; };   // 0..11 ps, 12 left, 13 right, 14 ctr, 15 ctr2

__launch_bounds__(128, 3)
__global__ void fusedlayer_k(const __bf16* __restrict__ feat,
                             const unsigned char* __restrict__ feat8,
                             const int* __restrict__ rp, const int* __restrict__ col,
                             FW fw, const float* __restrict__ gn1,
                             const float* __restrict__ gn2,
                             __bf16* __restrict__ outp,
                             unsigned char* __restrict__ out8, int M)
{
    __shared__ __bf16 wl[2][16 * WST];
    __shared__ unsigned char stage[2][16 * SST];
    const int tid = threadIdx.x, lane = tid & 63, wv = tid >> 6;
    const int r16 = lane & 15, kq = lane >> 4;
    const int wbase = blockIdx.x * 32 + wv * 16;
    const int wrow = (wbase + r16) < M ? (wbase + r16) : M - 1;
    unsigned char* st = stage[wv] + r16 * SST;

    f32x4 acc[8];
    #pragma unroll
    for (int n2 = 0; n2 < 8; ++n2) acc[n2] = (f32x4){0.f, 0.f, 0.f, 0.f};

    #pragma unroll
    for (int j = 0; j < 15; ++j) {
        float ss[32];
        if (j == 14) {       // self: own row from bf16 (coalesced, cache-friendly)
            const __bf16* sp = feat + (size_t)wrow * 128 + kq * 8;
            #pragma unroll
            for (int ks = 0; ks < 4; ++ks) {
                bf16x8 h = *reinterpret_cast<const bf16x8*>(sp + ks * 32);
                #pragma unroll
                for (int i = 0; i < 8; ++i) ss[ks * 8 + i] = (float)h[i];
            }
        } else {
            #pragma unroll
            for (int i = 0; i < 32; ++i) ss[i] = 0.f;
            const int b = rp[j * M + wrow], e = rp[j * M + wrow + 1];
            for (int t2 = b; t2 < e; ++t2) {
                // 4 kq-lanes cooperatively fetch the 128B fp8 row with
                // 2 x 64B-contiguous spans (2 coalesced requests, 1 line)
                const unsigned char* sp = feat8 + (size_t)col[t2] * 128;
                uint4 q0 = *reinterpret_cast<const uint4*>(sp + kq * 16);
                uint4 q1 = *reinterpret_cast<const uint4*>(sp + 64 + kq * 16);
                *reinterpret_cast<uint4*>(st + kq * 16) = q0;
                *reinterpret_cast<uint4*>(st + 64 + kq * 16) = q1;
                // read back this lane's A-frag byte slices (intra-wave LDS)
                #pragma unroll
                for (int ks = 0; ks < 4; ++ks) {
                    uint2 u = *reinterpret_cast<const uint2*>(st + ks * 32 + kq * 8);
                    f32x2 v0 = __builtin_amdgcn_cvt_pk_f32_fp8(u.x, false);
                    f32x2 v1 = __builtin_amdgcn_cvt_pk_f32_fp8(u.x, true);
                    f32x2 v2 = __builtin_amdgcn_cvt_pk_f32_fp8(u.y, false);
                    f32x2 v3 = __builtin_amdgcn_cvt_pk_f32_fp8(u.y, true);
                    ss[ks*8+0] += v0[0]; ss[ks*8+1] += v0[1];
                    ss[ks*8+2] += v1[0]; ss[ks*8+3] += v1[1];
                    ss[ks*8+4] += v2[0]; ss[ks*8+5] += v2[1];
                    ss[ks*8+6] += v3[0]; ss[ks*8+7] += v3[1];
                }
            }
        }
        bf16x8 a[4];
        ss_to_frags(ss, a);
        mfma16(acc, a, fw.w[j], lane);
    }

    // GN1 + relu -> wave LDS -> A-frags; ctr2 GEMM
    bf16x8 a2[4];
    gn_relayout(acc, gn1, wl[wv], a2, r16, kq);
    f32x4 acc2[8];
    #pragma unroll
    for (int n2 = 0; n2 < 8; ++n2) acc2[n2] = (f32x4){0.f, 0.f, 0.f, 0.f};
    mfma16(acc2, a2, fw.w[15], lane);

    // GN2 + residual + relu -> out (bf16 + fp8 shadow)
    float m[4], inv[4];
    gn_mi(acc2, m, inv);
    #pragma unroll
    for (int reg = 0; reg < 4; ++reg) {
        const int crow = wbase + kq * 4 + reg;
        if (crow < M) {
            __bf16* dp = outp + (size_t)crow * 128 + r16;
            unsigned char* d8 = out8 + (size_t)crow * 128 + r16;
            const __bf16* rs = feat + (size_t)crow * 128 + r16;
            #pragma unroll
            for (int n2 = 0; n2 < 8; ++n2) {
                const int colc = n2 * 16 + r16;
                float y = (acc2[n2][reg] - m[reg]) * inv[reg] * gn2[colc] + gn2[128 + colc];
                y += (float)rs[n2 * 16];
                y = fmaxf(y, 0.f);
                dp[n2 * 16] = (__bf16)y;
                d8[n2 * 16] = (unsigned char)f32_to_fp8(y);
            }
        }
    }
}

// ============= lptail: lane_pooling tail (R9 + optional fp8 shadow) =========
template<bool LP2>
__launch_bounds__(128, 3)
__global__ void lptail_k(const __bf16* __restrict__ hsrc,
                         const int* __restrict__ rp, const int* __restrict__ col,
                         const float* __restrict__ roi,
                         const __bf16* __restrict__ wc2, const __bf16* __restrict__ winW,
                         const __bf16* __restrict__ wm1, const __bf16* __restrict__ wm2,
                         const float* __restrict__ ngn, const float* __restrict__ m1gn,
                         const float* __restrict__ m2gn,
                         void* __restrict__ outp,
                         unsigned char* __restrict__ out8, int M)
{
    __shared__ __bf16 wl[2][16 * WST];
    const int tid = threadIdx.x, lane = tid & 63, wv = tid >> 6;
    const int r16 = lane & 15, kq = lane >> 4;
    const int wbase = blockIdx.x * 32 + wv * 16;
    const int wrow = (wbase + r16) < M ? (wbase + r16) : M - 1;

    f32x4 acc[8];
    #pragma unroll
    for (int n2 = 0; n2 < 8; ++n2) acc[n2] = (f32x4){0.f, 0.f, 0.f, 0.f};

    {   // (Σ h) @ c2
        float ss[32];
        #pragma unroll
        for (int i = 0; i < 32; ++i) ss[i] = 0.f;
        const int b = rp[wrow], e = rp[wrow + 1];
        for (int t2 = b; t2 < e; ++t2) {
            const __bf16* sp = hsrc + (size_t)col[t2] * 128 + kq * 8;
            #pragma unroll
            for (int ks = 0; ks < 4; ++ks) {
                bf16x8 h = *reinterpret_cast<const bf16x8*>(sp + ks * 32);
                #pragma unroll
                for (int i = 0; i < 8; ++i) ss[ks * 8 + i] += (float)h[i];
            }
        }
        bf16x8 a[4];
        ss_to_frags(ss, a);
        mfma16(acc, a, wc2, lane);
    }
    if (LP2) {   // + roi @ input_w
        bf16x8 a[4];
        const float* sp = roi + (size_t)wrow * 128 + kq * 8;
        #pragma unroll
        for (int ks = 0; ks < 4; ++ks) a[ks] = cvt8(sp + ks * 32);
        mfma16(acc, a, winW, lane);
    }

    {   // relu(gn(.,ngn)) @ m1
        bf16x8 a[4];
        gn_relayout(acc, ngn, wl[wv], a, r16, kq);
        #pragma unroll
        for (int n2 = 0; n2 < 8; ++n2) acc[n2] = (f32x4){0.f, 0.f, 0.f, 0.f};
        mfma16(acc, a, wm1, lane);
    }
    {   // relu(gn(.,m1gn)) @ m2
        bf16x8 a[4];
        gn_relayout(acc, m1gn, wl[wv], a, r16, kq);
        #pragma unroll
        for (int n2 = 0; n2 < 8; ++n2) acc[n2] = (f32x4){0.f, 0.f, 0.f, 0.f};
        mfma16(acc, a, wm2, lane);
    }

    float m[4], inv[4];
    gn_mi(acc, m, inv);
    #pragma unroll
    for (int reg = 0; reg < 4; ++reg) {
        const int crow = wbase + kq * 4 + reg;
        if (crow < M) {
            #pragma unroll
            for (int n2 = 0; n2 < 8; ++n2) {
                const int colc = n2 * 16 + r16;
                float y = (acc[n2][reg] - m[reg]) * inv[reg] * m2gn[colc] + m2gn[128 + colc];
                if (LP2) {
                    y += roi[(size_t)crow * 128 + colc];
                    ((float*)outp)[(size_t)crow * 128 + colc] = fmaxf(y, 0.f);
                } else {
                    y = fmaxf(y, 0.f);
                    ((__bf16*)outp)[(size_t)crow * 128 + colc] = (__bf16)y;
                    out8[(size_t)crow * 128 + colc] = (unsigned char)f32_to_fp8(y);
                }
            }
        }
    }
}

// ===========================================================================
extern "C" void kernel_launch(void* const* d_in, const int* in_sizes, int n_in,
                              void* d_out, int out_size, void* d_ws, size_t ws_size,
                              hipStream_t stream)
{
    const float* roi_feat   = (const float*)d_in[0];
    const float* graph_pose = (const float*)d_in[1];
    const float* roi_pose   = (const float*)d_in[2];
    const float* lp_input_w = (const float*)d_in[3];
    const float* lp_rpw     = (const float*)d_in[4];
    const float* lp_rpb     = (const float*)d_in[5];
    const float* lp_c1w     = (const float*)d_in[6];
    const float* lp_c1gn    = (const float*)d_in[7];
    const float* lp_c2w     = (const float*)d_in[8];
    const float* lp_m1w     = (const float*)d_in[9];
    const float* lp_m1gn    = (const float*)d_in[10];
    const float* lp_m2w     = (const float*)d_in[11];
    const float* lp_m2gn    = (const float*)d_in[12];
    const float* lp_ngn     = (const float*)d_in[13];
    const float* f_ctrw     = (const float*)d_in[14];
    const float* f_psw      = (const float*)d_in[15];
    const float* f_lw       = (const float*)d_in[16];
    const float* f_rw       = (const float*)d_in[17];
    const float* f_ngn      = (const float*)d_in[18];
    const float* f_c2w      = (const float*)d_in[19];
    const float* f_c2gn     = (const float*)d_in[20];
    const int* e1_hi = (const int*)d_in[21];
    const int* e1_wi = (const int*)d_in[22];
    const int* e2_hi = (const int*)d_in[23];
    const int* e2_wi = (const int*)d_in[24];
    const int* ps_u  = (const int*)d_in[25];
    const int* ps_v  = (const int*)d_in[26];
    const int* lr_u  = (const int*)d_in[27];
    const int* lr_v  = (const int*)d_in[28];
    float* out = (float*)d_out;

    // ---- workspace (~90 MB) ----
    __bf16* gA   = (__bf16*)d_ws;                       // NG*128
    __bf16* gB   = gA + (size_t)NG * 128;               // NG*128
    __bf16* hbuf = gB + (size_t)NG * 128;               // E1_N*128
    __bf16* wbuf = hbuf + (size_t)E1_N * 128;           // 80*16384
    unsigned char* g8A = (unsigned char*)(wbuf + (size_t)80 * 16384); // NG*128 B
    unsigned char* g8B = g8A + (size_t)NG * 128;                      // NG*128 B
    int* ip      = (int*)(g8B + (size_t)NG * 128);
    int* cnt14   = ip;             ip += 14 * NG;
    int* rp14    = ip;             ip += 14 * NG + 1;
    int* col14   = ip;             ip += 12 * EPS_N + 2 * ELR_N;
    int* cntE1   = ip;             ip += NG;
    int* rpE1    = ip;             ip += NG + 1;
    int* colE1   = ip;             ip += E1_N;
    int* cntE2   = ip;             ip += NR;
    int* rpE2    = ip;             ip += NR + 1;
    int* colE2   = ip;             ip += E2_N;
    int* bsum    = ip;             ip += 256;

    dim3 blk(256), blk128(128);
    const dim3 gNG32((NG + 31) / 32), gNR32((NR + 31) / 32), gE32((E1_N + 31) / 32);
    const int NE14 = 12 * EPS_N + 2 * ELR_N;
    const dim3 gH14((NE14 + 255) / 256);

    // ---------------- weight prep ----------------
    PrepTab tab; int nw = 0;
    auto addw = [&](const float* p, int s) { tab.src[nw] = p; tab.stride[nw] = s; ++nw; };
    addw(lp_c1w, 256);                 // 0 c1A_0
    addw(lp_c1w + 128, 256);           // 1 c1B_0
    addw(lp_c1w + 32768, 256);         // 2 c1A_1
    addw(lp_c1w + 32768 + 128, 256);   // 3 c1B_1
    addw(lp_input_w + 16384, 128);     // 4 input_w[1]
    addw(lp_c2w, 128); addw(lp_c2w + 16384, 128);   // 5,6
    addw(lp_m1w, 128); addw(lp_m1w + 16384, 128);   // 7,8
    addw(lp_m2w, 128); addw(lp_m2w + 16384, 128);   // 9,10
    for (int i = 0; i < 4; ++i) addw(f_ctrw + (size_t)i * 16384, 128);      // 11..14
    for (int i = 0; i < 4; ++i)
        for (int k = 0; k < 12; ++k) addw(f_psw + ((size_t)i * 12 + k) * 16384, 128);
    for (int i = 0; i < 4; ++i) addw(f_lw + (size_t)i * 16384, 128);        // 63..66
    for (int i = 0; i < 4; ++i) addw(f_rw + (size_t)i * 16384, 128);        // 67..70
    for (int i = 0; i < 4; ++i) addw(f_c2w + (size_t)i * 16384, 128);       // 71..74
    tab.n = nw;
    auto wb = [&](int idx) { return (const __bf16*)(wbuf + (size_t)idx * 16384); };
    prepw_k<<<dim3((nw * 2048 + 255) / 256), blk, 0, stream>>>(tab, wbuf);

    // ---------------- CSR builds ----------------
    hipMemsetAsync(cnt14, 0, (size_t)14 * NG * 4, stream);
    hist14_k<<<gH14, blk, 0, stream>>>(ps_u, lr_u, cnt14);
    {
        int n = 14 * NG, nb = (n + SCAN_CHUNK - 1) / SCAN_CHUNK;
        scan1_k<<<nb, blk, 0, stream>>>(cnt14, n, bsum);
        scan2_k<<<1, blk, 0, stream>>>(bsum, nb);
        scan3_k<<<nb, blk, 0, stream>>>(cnt14, n, bsum, rp14);
    }
    hipMemcpyAsync(cnt14, rp14, (size_t)14 * NG * 4, hipMemcpyDeviceToDevice, stream);
    fill14_k<<<gH14, blk, 0, stream>>>(ps_u, ps_v, lr_u, lr_v, cnt14, col14);

    hipMemsetAsync(cntE1, 0, (size_t)NG * 4, stream);
    histE_k<<<(E1_N + 255) / 256, blk, 0, stream>>>(e1_wi, E1_N, cntE1);
    {
        int n = NG, nb = (n + SCAN_CHUNK - 1) / SCAN_CHUNK;
        scan1_k<<<nb, blk, 0, stream>>>(cntE1, n, bsum);
        scan2_k<<<1, blk, 0, stream>>>(bsum, nb);
        scan3_k<<<nb, blk, 0, stream>>>(cntE1, n, bsum, rpE1);
    }
    hipMemcpyAsync(cntE1, rpE1, (size_t)NG * 4, hipMemcpyDeviceToDevice, stream);
    fillE_k<<<(E1_N + 255) / 256, blk, 0, stream>>>(e1_wi, E1_N, cntE1, colE1);

    hipMemsetAsync(cntE2, 0, (size_t)NR * 4, stream);
    histE_k<<<(E2_N + 255) / 256, blk, 0, stream>>>(e2_wi, E2_N, cntE2);
    {
        int n = NR, nb = (n + SCAN_CHUNK - 1) / SCAN_CHUNK;
        scan1_k<<<nb, blk, 0, stream>>>(cntE2, n, bsum);
        scan2_k<<<1, blk, 0, stream>>>(bsum, nb);
        scan3_k<<<nb, blk, 0, stream>>>(cntE2, n, bsum, rpE2);
    }
    hipMemcpyAsync(cntE2, rpE2, (size_t)NR * 4, hipMemcpyDeviceToDevice, stream);
    fillE_k<<<(E2_N + 255) / 256, blk, 0, stream>>>(e2_wi, E2_N, cntE2, colE2);

    // ---------------- lane_pooling #1 (roi -> graph) ----------------
    edgefull_k<float><<<gE32, blk128, 0, stream>>>(
        e1_hi, e1_wi, roi_feat, roi_pose, graph_pose, lp_rpw, lp_rpb,
        wb(0), wb(1), lp_c1gn, hbuf, E1_N);
    lptail_k<false><<<gNG32, blk128, 0, stream>>>(
        hbuf, rpE1, colE1, nullptr, wb(5), nullptr, wb(7), wb(9),
        lp_ngn, lp_m1gn, lp_m2gn, gA, g8A, NG);

    // ---------------- global_graph: 4 fused layers ----------------
    for (int i = 0; i < 4; ++i) {
        FW fw;
        for (int k = 0; k < 12; ++k) fw.w[k] = wb(15 + i * 12 + k);
        fw.w[12] = wb(63 + i); fw.w[13] = wb(67 + i);
        fw.w[14] = wb(11 + i); fw.w[15] = wb(71 + i);
        const __bf16* src = (i & 1) ? gB : gA;
        __bf16* dst = (i & 1) ? gA : gB;
        const unsigned char* src8 = (i & 1) ? g8B : g8A;
        unsigned char* dst8 = (i & 1) ? g8A : g8B;
        fusedlayer_k<<<gNG32, blk128, 0, stream>>>(
            src, src8, rp14, col14, fw, f_ngn + (size_t)i * 256,
            f_c2gn + (size_t)i * 256, dst, dst8, NG);
    }
    // after i=3: result in gA

    // ---------------- lane_pooling #2 (graph -> roi) ----------------
    edgefull_k<__bf16><<<gE32, blk128, 0, stream>>>(
        e2_hi, e2_wi, gA, graph_pose, roi_pose, lp_rpw + 512, lp_rpb + 128,
        wb(2), wb(3), lp_c1gn + 256, hbuf, E2_N);
    lptail_k<true><<<gNR32, blk128, 0, stream>>>(
        hbuf, rpE2, colE2, roi_feat, wb(6), wb(4), wb(8), wb(10),
        lp_ngn + 256, lp_m1gn + 256, lp_m2gn + 256, out, nullptr, NR);
}

// Round 16
// 656.438 us; speedup vs baseline: 1.8561x; 1.0654x over previous
//
#include <hip/hip_runtime.h>

#define NG 50000
#define NR 12000
#define EPS_N 50000
#define ELR_N 5000
#define E1_N 150000
#define E2_N 150000
#define GN_EPS_F 1e-5f
#define SCAN_CHUNK 4096
#define WST 136    // wave-LDS tile row stride (bf16 elems)
#define SST 176    // fp8 staging row stride (bytes)

// combined CSR geometry
#define NKEY (14 * NG + NG + NR)            // 762000 counters
#define NEDGE (12 * EPS_N + 2 * ELR_N + E1_N + E2_N)   // 910000 edges
#define E1OFF (12 * EPS_N + 2 * ELR_N)      // 610000
#define E2OFF (E1OFF + E1_N)                // 760000

typedef __attribute__((ext_vector_type(8))) __bf16 bf16x8;
typedef __attribute__((ext_vector_type(4))) float f32x4;
typedef __attribute__((ext_vector_type(2))) float f32x2;

__device__ __forceinline__ bf16x8 cvt8(const float* __restrict__ p) {
    float4 x0 = *reinterpret_cast<const float4*>(p);
    float4 x1 = *reinterpret_cast<const float4*>(p + 4);
    bf16x8 a;
    a[0] = (__bf16)x0.x; a[1] = (__bf16)x0.y; a[2] = (__bf16)x0.z; a[3] = (__bf16)x0.w;
    a[4] = (__bf16)x1.x; a[5] = (__bf16)x1.y; a[6] = (__bf16)x1.z; a[7] = (__bf16)x1.w;
    return a;
}

// ---------- manual OCP e4m3 quantizer (values are post-relu, >= 0) ----------
__device__ __forceinline__ unsigned f32_to_fp8(float f) {
    f = fminf(f, 448.f);
    unsigned bits = __float_as_uint(f);
    int e = (int)((bits >> 23) & 0xff) - 127;
    if (e < -9) return 0u;
    if (e < -6) return (unsigned)(int)(f * 512.f + 0.5f);
    unsigned m = (bits >> 20) & 7;
    unsigned r = (bits >> 19) & 1;
    unsigned em = ((unsigned)(e + 7) << 3) | m;
    em += r;
    if (em > 0x7Eu) em = 0x7Eu;
    return em;
}

// ====== weight prep: f32 -> fragment-major bf16 (global, coalesced reads) ===
struct PrepTab { const float* src[80]; int stride[80]; int n; };

__global__ void prepw_k(PrepTab tab, __bf16* __restrict__ wbuf)
{
    int t = blockIdx.x * 256 + threadIdx.x;
    int w = t >> 11;
    if (w >= tab.n) return;
    int rr = t & 2047;
    int chunk = rr >> 6, l = rr & 63;
    int wn = chunk >> 4, ks = (chunk >> 2) & 3, ni = chunk & 3;
    int c = wn * 64 + ni * 16 + (l & 15);
    int kb = (ks * 4 + (l >> 4)) * 8;
    const float* s = tab.src[w] + (size_t)c * tab.stride[w] + kb;
    bf16x8 o;
    #pragma unroll
    for (int e = 0; e < 8; ++e) o[e] = (__bf16)s[e];
    *reinterpret_cast<bf16x8*>(wbuf + (size_t)w * 16384 + rr * 8) = o;
}

// ================= combined CSR construction (one pipeline) =================
__device__ __forceinline__ int edge_key(int t, const int* ps_u, const int* lr_u,
                                        const int* e1_wi, const int* e2_wi)
{
    if (t < 12 * EPS_N) return (t / EPS_N) * NG + ps_u[t];
    if (t < E1OFF) { int r = t - 12 * EPS_N; return (12 + r / ELR_N) * NG + lr_u[r]; }
    if (t < E2OFF) return 14 * NG + e1_wi[t - E1OFF];
    return 14 * NG + NG + e2_wi[t - E2OFF];
}

__global__ void histA_k(const int* __restrict__ ps_u, const int* __restrict__ lr_u,
                        const int* __restrict__ e1_wi, const int* __restrict__ e2_wi,
                        int* __restrict__ cnt)
{
    int t = blockIdx.x * 256 + threadIdx.x;
    if (t >= NEDGE) return;
    atomicAdd(&cnt[edge_key(t, ps_u, lr_u, e1_wi, e2_wi)], 1);
}

__global__ void fillA_k(const int* __restrict__ ps_u, const int* __restrict__ lr_u,
                        const int* __restrict__ e1_wi, const int* __restrict__ e2_wi,
                        const int* __restrict__ ps_v, const int* __restrict__ lr_v,
                        int* __restrict__ head, int* __restrict__ col)
{
    int t = blockIdx.x * 256 + threadIdx.x;
    if (t >= NEDGE) return;
    int payload;
    if (t < 12 * EPS_N) payload = ps_v[t];
    else if (t < E1OFF) payload = lr_v[t - 12 * EPS_N];
    else if (t < E2OFF) payload = t - E1OFF;    // e1 edge id
    else payload = t - E2OFF;                   // e2 edge id
    int pos = atomicAdd(&head[edge_key(t, ps_u, lr_u, e1_wi, e2_wi)], 1);
    col[pos] = payload;
}

__global__ void scan1_k(const int* __restrict__ in, int n, int* __restrict__ bsum)
{
    __shared__ int sm[4];
    int base = blockIdx.x * SCAN_CHUNK;
    int s = 0;
    for (int i = threadIdx.x; i < SCAN_CHUNK; i += 256) {
        int idx = base + i;
        s += (idx < n) ? in[idx] : 0;
    }
    #pragma unroll
    for (int off = 1; off < 64; off <<= 1) s += __shfl_xor(s, off);
    if ((threadIdx.x & 63) == 0) sm[threadIdx.x >> 6] = s;
    __syncthreads();
    if (threadIdx.x == 0) bsum[blockIdx.x] = sm[0] + sm[1] + sm[2] + sm[3];
}

__global__ void scan2_k(int* __restrict__ bsum, int nb)
{
    if (threadIdx.x == 0) {
        int acc = 0;
        for (int i = 0; i < nb; ++i) { int t = bsum[i]; bsum[i] = acc; acc += t; }
    }
}

__global__ void scan3_k(const int* __restrict__ in, int n,
                        const int* __restrict__ bsum, int* __restrict__ outp)
{
    __shared__ int sm[256];
    int base = blockIdx.x * SCAN_CHUNK;
    int loc[16]; int s = 0;
    #pragma unroll
    for (int i = 0; i < 16; ++i) {
        int idx = base + threadIdx.x * 16 + i;
        loc[i] = (idx < n) ? in[idx] : 0; s += loc[i];
    }
    sm[threadIdx.x] = s; __syncthreads();
    for (int off = 1; off < 256; off <<= 1) {
        int v = (threadIdx.x >= off) ? sm[threadIdx.x - off] : 0;
        __syncthreads();
        sm[threadIdx.x] += v;
        __syncthreads();
    }
    int tp = (threadIdx.x ? sm[threadIdx.x - 1] : 0) + bsum[blockIdx.x];
    #pragma unroll
    for (int i = 0; i < 16; ++i) {
        int idx = base + threadIdx.x * 16 + i;
        if (idx < n) outp[idx] = tp;
        tp += loc[i];
        if (idx == n - 1) outp[n] = tp;
    }
}

// ================ wave-autonomous GEMM helpers (BM=16 per wave) =============
__device__ __forceinline__ void mfma16(f32x4 (&acc)[8], const bf16x8 (&a)[4],
                                       const __bf16* __restrict__ gw, int lane)
{
    const __bf16* gwb = gw + lane * 8;
    #pragma unroll
    for (int ks = 0; ks < 4; ++ks) {
        #pragma unroll
        for (int n2 = 0; n2 < 8; ++n2) {
            const int chunk = (n2 >> 2) * 16 + ks * 4 + (n2 & 3);
            bf16x8 b = *reinterpret_cast<const bf16x8*>(gwb + chunk * 512);
            acc[n2] = __builtin_amdgcn_mfma_f32_16x16x32_bf16(a[ks], b, acc[n2], 0, 0, 0);
        }
    }
}

__device__ __forceinline__ void ss_to_frags(const float (&ss)[32], bf16x8 (&a)[4])
{
    #pragma unroll
    for (int ks = 0; ks < 4; ++ks)
        #pragma unroll
        for (int i = 0; i < 8; ++i)
            a[ks][i] = (__bf16)ss[ks * 8 + i];
}

__device__ __forceinline__ void gn_mi(const f32x4 (&acc)[8], float (&m)[4], float (&inv)[4])
{
    #pragma unroll
    for (int reg = 0; reg < 4; ++reg) {
        float s = 0.f, q = 0.f;
        #pragma unroll
        for (int n2 = 0; n2 < 8; ++n2) { float v = acc[n2][reg]; s += v; q = fmaf(v, v, q); }
        #pragma unroll
        for (int off = 1; off < 16; off <<= 1) {
            s += __shfl_xor(s, off);
            q += __shfl_xor(q, off);
        }
        m[reg] = s * (1.f / 128.f);
        inv[reg] = rsqrtf(fmaxf(q * (1.f / 128.f) - m[reg] * m[reg], 0.f) + GN_EPS_F);
    }
}

__device__ __forceinline__ void gn_relayout(const f32x4 (&acc)[8], const float* __restrict__ sb,
                                            __bf16* wl, bf16x8 (&a)[4], int r16, int kq)
{
    float m[4], inv[4];
    gn_mi(acc, m, inv);
    #pragma unroll
    for (int reg = 0; reg < 4; ++reg) {
        #pragma unroll
        for (int n2 = 0; n2 < 8; ++n2) {
            const int colc = n2 * 16 + r16;
            float y = (acc[n2][reg] - m[reg]) * inv[reg] * sb[colc] + sb[128 + colc];
            wl[(kq * 4 + reg) * WST + colc] = (__bf16)fmaxf(y, 0.f);
        }
    }
    #pragma unroll
    for (int ks = 0; ks < 4; ++ks)
        a[ks] = *reinterpret_cast<const bf16x8*>(wl + r16 * WST + ks * 32 + kq * 8);
}

// ============ edgefull: h[e] = relu(gn(ctx[hi]@c1A + dist@c1B, sb)) =========
template<typename CT>
__launch_bounds__(128, 3)
__global__ void edgefull_k(const int* __restrict__ hi_idx, const int* __restrict__ wi_idx,
                           const CT* __restrict__ ctxfeat,
                           const float* __restrict__ cpose, const float* __restrict__ tpose,
                           const float* __restrict__ rpw, const float* __restrict__ rpb,
                           const __bf16* __restrict__ wc1A, const __bf16* __restrict__ wc1B,
                           const float* __restrict__ sb,
                           __bf16* __restrict__ hout, int M)
{
    __shared__ float rw[640];
    const int tid = threadIdx.x, lane = tid & 63, wv = tid >> 6;
    const int r16 = lane & 15, kq = lane >> 4;
    const int wbase = blockIdx.x * 32 + wv * 16;
    const int erow = wbase + r16;
    const int ec = erow < M ? erow : M - 1;

    for (int i = tid; i < 640; i += 128)
        rw[i] = (i < 512) ? rpw[i] : rpb[i - 512];
    __syncthreads();

    const int hi = hi_idx[ec], wi = wi_idx[ec];
    float4 cp = *reinterpret_cast<const float4*>(cpose + (size_t)hi * 4);
    float4 tp = *reinterpret_cast<const float4*>(tpose + (size_t)wi * 4);
    const float d0 = cp.x - tp.x, d1 = cp.y - tp.y, d2 = cp.z - tp.z, d3 = cp.w - tp.w;

    f32x4 acc[8];
    #pragma unroll
    for (int n2 = 0; n2 < 8; ++n2) acc[n2] = (f32x4){0.f, 0.f, 0.f, 0.f};

    {   // ctx[hi] @ c1A
        bf16x8 a[4];
        const CT* sp = ctxfeat + (size_t)hi * 128 + kq * 8;
        #pragma unroll
        for (int ks = 0; ks < 4; ++ks) {
            if constexpr (sizeof(CT) == 4) a[ks] = cvt8((const float*)sp + ks * 32);
            else a[ks] = *reinterpret_cast<const bf16x8*>((const __bf16*)sp + ks * 32);
        }
        mfma16(acc, a, wc1A, lane);
    }
    {   // dist @ c1B (A built in-register)
        bf16x8 a[4];
        #pragma unroll
        for (int ks = 0; ks < 4; ++ks)
            #pragma unroll
            for (int i = 0; i < 8; ++i) {
                const int k = ks * 32 + kq * 8 + i;
                float4 w4 = *reinterpret_cast<const float4*>(&rw[k * 4]);
                float d = fmaf(d0, w4.x, fmaf(d1, w4.y, fmaf(d2, w4.z,
                          fmaf(d3, w4.w, rw[512 + k]))));
                a[ks][i] = (__bf16)fmaxf(d, 0.f);
            }
        mfma16(acc, a, wc1B, lane);
    }

    float m[4], inv[4];
    gn_mi(acc, m, inv);
    #pragma unroll
    for (int reg = 0; reg < 4; ++reg) {
        const int crow = wbase + kq * 4 + reg;
        if (crow < M) {
            __bf16* dp = hout + (size_t)crow * 128 + r16;
            #pragma unroll
            for (int n2 = 0; n2 < 8; ++n2) {
                const int colc = n2 * 16 + r16;
                float y = (acc[n2][reg] - m[reg]) * inv[reg] * sb[colc] + sb[128 + colc];
                dp[n2 * 16] = (__bf16)fmaxf(y, 0.f);
            }
        }
    }
}

// ======= fusedlayer: fp8 gathers, 2x16B row loads + double-buffered LDS =====
struct FW { const __bf16* w[16]; };   // 0..11 ps, 12 left, 13 right, 14 ctr, 15 ctr2

__launch_bounds__(128, 3)
__global__ void fusedlayer_k(const __bf16* __restrict__ feat,
                             const unsigned char* __restrict__ feat8,
                             const int* __restrict__ rp, const int* __restrict__ col,
                             FW fw, const float* __restrict__ gn1,
                             const float* __restrict__ gn2,
                             __bf16* __restrict__ outp,
                             unsigned char* __restrict__ out8, int M)
{
    __shared__ __bf16 wl[2][16 * WST];
    __shared__ unsigned char stage[2][2][16 * SST];
    const int tid = threadIdx.x, lane = tid & 63, wv = tid >> 6;
    const int r16 = lane & 15, kq = lane >> 4;
    const int wbase = blockIdx.x * 32 + wv * 16;
    const int wrow = (wbase + r16) < M ? (wbase + r16) : M - 1;

    f32x4 acc[8];
    #pragma unroll
    for (int n2 = 0; n2 < 8; ++n2) acc[n2] = (f32x4){0.f, 0.f, 0.f, 0.f};

    int sc = 0;   // rotating staging buffer selector (breaks LDS WAR chain)

    #pragma unroll
    for (int j = 0; j < 15; ++j) {
        float ss[32];
        if (j == 14) {       // self: own row from bf16
            const __bf16* sp = feat + (size_t)wrow * 128 + kq * 8;
            #pragma unroll
            for (int ks = 0; ks < 4; ++ks) {
                bf16x8 h = *reinterpret_cast<const bf16x8*>(sp + ks * 32);
                #pragma unroll
                for (int i = 0; i < 8; ++i) ss[ks * 8 + i] = (float)h[i];
            }
        } else {
            #pragma unroll
            for (int i = 0; i < 32; ++i) ss[i] = 0.f;
            const int b = rp[j * M + wrow], e = rp[j * M + wrow + 1];
            for (int t2 = b; t2 < e; ++t2) {
                unsigned char* st = stage[wv][sc & 1] + r16 * SST;
                sc++;
                const unsigned char* sp = feat8 + (size_t)col[t2] * 128;
                uint4 q0 = *reinterpret_cast<const uint4*>(sp + kq * 16);
                uint4 q1 = *reinterpret_cast<const uint4*>(sp + 64 + kq * 16);
                *reinterpret_cast<uint4*>(st + kq * 16) = q0;
                *reinterpret_cast<uint4*>(st + 64 + kq * 16) = q1;
                #pragma unroll
                for (int ks = 0; ks < 4; ++ks) {
                    uint2 u = *reinterpret_cast<const uint2*>(st + ks * 32 + kq * 8);
                    f32x2 v0 = __builtin_amdgcn_cvt_pk_f32_fp8(u.x, false);
                    f32x2 v1 = __builtin_amdgcn_cvt_pk_f32_fp8(u.x, true);
                    f32x2 v2 = __builtin_amdgcn_cvt_pk_f32_fp8(u.y, false);
                    f32x2 v3 = __builtin_amdgcn_cvt_pk_f32_fp8(u.y, true);
                    ss[ks*8+0] += v0[0]; ss[ks*8+1] += v0[1];
                    ss[ks*8+2] += v1[0]; ss[ks*8+3] += v1[1];
                    ss[ks*8+4] += v2[0]; ss[ks*8+5] += v2[1];
                    ss[ks*8+6] += v3[0]; ss[ks*8+7] += v3[1];
                }
            }
        }
        bf16x8 a[4];
        ss_to_frags(ss, a);
        mfma16(acc, a, fw.w[j], lane);
    }

    // GN1 + relu -> wave LDS -> A-frags; ctr2 GEMM
    bf16x8 a2[4];
    gn_relayout(acc, gn1, wl[wv], a2, r16, kq);
    f32x4 acc2[8];
    #pragma unroll
    for (int n2 = 0; n2 < 8; ++n2) acc2[n2] = (f32x4){0.f, 0.f, 0.f, 0.f};
    mfma16(acc2, a2, fw.w[15], lane);

    // GN2 + residual + relu -> out (bf16 + fp8 shadow)
    float m[4], inv[4];
    gn_mi(acc2, m, inv);
    #pragma unroll
    for (int reg = 0; reg < 4; ++reg) {
        const int crow = wbase + kq * 4 + reg;
        if (crow < M) {
            __bf16* dp = outp + (size_t)crow * 128 + r16;
            unsigned char* d8 = out8 + (size_t)crow * 128 + r16;
            const __bf16* rs = feat + (size_t)crow * 128 + r16;
            #pragma unroll
            for (int n2 = 0; n2 < 8; ++n2) {
                const int colc = n2 * 16 + r16;
                float y = (acc2[n2][reg] - m[reg]) * inv[reg] * gn2[colc] + gn2[128 + colc];
                y += (float)rs[n2 * 16];
                y = fmaxf(y, 0.f);
                dp[n2 * 16] = (__bf16)y;
                d8[n2 * 16] = (unsigned char)f32_to_fp8(y);
            }
        }
    }
}

// ============= lptail: lane_pooling tail (R9 + optional fp8 shadow) =========
template<bool LP2>
__launch_bounds__(128, 3)
__global__ void lptail_k(const __bf16* __restrict__ hsrc,
                         const int* __restrict__ rp, const int* __restrict__ col,
                         const float* __restrict__ roi,
                         const __bf16* __restrict__ wc2, const __bf16* __restrict__ winW,
                         const __bf16* __restrict__ wm1, const __bf16* __restrict__ wm2,
                         const float* __restrict__ ngn, const float* __restrict__ m1gn,
                         const float* __restrict__ m2gn,
                         void* __restrict__ outp,
                         unsigned char* __restrict__ out8, int M)
{
    __shared__ __bf16 wl[2][16 * WST];
    const int tid = threadIdx.x, lane = tid & 63, wv = tid >> 6;
    const int r16 = lane & 15, kq = lane >> 4;
    const int wbase = blockIdx.x * 32 + wv * 16;
    const int wrow = (wbase + r16) < M ? (wbase + r16) : M - 1;

    f32x4 acc[8];
    #pragma unroll
    for (int n2 = 0; n2 < 8; ++n2) acc[n2] = (f32x4){0.f, 0.f, 0.f, 0.f};

    {   // (Σ h) @ c2
        float ss[32];
        #pragma unroll
        for (int i = 0; i < 32; ++i) ss[i] = 0.f;
        const int b = rp[wrow], e = rp[wrow + 1];
        for (int t2 = b; t2 < e; ++t2) {
            const __bf16* sp = hsrc + (size_t)col[t2] * 128 + kq * 8;
            #pragma unroll
            for (int ks = 0; ks < 4; ++ks) {
                bf16x8 h = *reinterpret_cast<const bf16x8*>(sp + ks * 32);
                #pragma unroll
                for (int i = 0; i < 8; ++i) ss[ks * 8 + i] += (float)h[i];
            }
        }
        bf16x8 a[4];
        ss_to_frags(ss, a);
        mfma16(acc, a, wc2, lane);
    }
    if (LP2) {   // + roi @ input_w
        bf16x8 a[4];
        const float* sp = roi + (size_t)wrow * 128 + kq * 8;
        #pragma unroll
        for (int ks = 0; ks < 4; ++ks) a[ks] = cvt8(sp + ks * 32);
        mfma16(acc, a, winW, lane);
    }

    {   // relu(gn(.,ngn)) @ m1
        bf16x8 a[4];
        gn_relayout(acc, ngn, wl[wv], a, r16, kq);
        #pragma unroll
        for (int n2 = 0; n2 < 8; ++n2) acc[n2] = (f32x4){0.f, 0.f, 0.f, 0.f};
        mfma16(acc, a, wm1, lane);
    }
    {   // relu(gn(.,m1gn)) @ m2
        bf16x8 a[4];
        gn_relayout(acc, m1gn, wl[wv], a, r16, kq);
        #pragma unroll
        for (int n2 = 0; n2 < 8; ++n2) acc[n2] = (f32x4){0.f, 0.f, 0.f, 0.f};
        mfma16(acc, a, wm2, lane);
    }

    float m[4], inv[4];
    gn_mi(acc, m, inv);
    #pragma unroll
    for (int reg = 0; reg < 4; ++reg) {
        const int crow = wbase + kq * 4 + reg;
        if (crow < M) {
            #pragma unroll
            for (int n2 = 0; n2 < 8; ++n2) {
                const int colc = n2 * 16 + r16;
                float y = (acc[n2][reg] - m[reg]) * inv[reg] * m2gn[colc] + m2gn[128 + colc];
                if (LP2) {
                    y += roi[(size_t)crow * 128 + colc];
                    ((float*)outp)[(size_t)crow * 128 + colc] = fmaxf(y, 0.f);
                } else {
                    y = fmaxf(y, 0.f);
                    ((__bf16*)outp)[(size_t)crow * 128 + colc] = (__bf16)y;
                    out8[(size_t)crow * 128 + colc] = (unsigned char)f32_to_fp8(y);
                }
            }
        }
    }
}

// ===========================================================================
extern "C" void kernel_launch(void* const* d_in, const int* in_sizes, int n_in,
                              void* d_out, int out_size, void* d_ws, size_t ws_size,
                              hipStream_t stream)
{
    const float* roi_feat   = (const float*)d_in[0];
    const float* graph_pose = (const float*)d_in[1];
    const float* roi_pose   = (const float*)d_in[2];
    const float* lp_input_w = (const float*)d_in[3];
    const float* lp_rpw     = (const float*)d_in[4];
    const float* lp_rpb     = (const float*)d_in[5];
    const float* lp_c1w     = (const float*)d_in[6];
    const float* lp_c1gn    = (const float*)d_in[7];
    const float* lp_c2w     = (const float*)d_in[8];
    const float* lp_m1w     = (const float*)d_in[9];
    const float* lp_m1gn    = (const float*)d_in[10];
    const float* lp_m2w     = (const float*)d_in[11];
    const float* lp_m2gn    = (const float*)d_in[12];
    const float* lp_ngn     = (const float*)d_in[13];
    const float* f_ctrw     = (const float*)d_in[14];
    const float* f_psw      = (const float*)d_in[15];
    const float* f_lw       = (const float*)d_in[16];
    const float* f_rw       = (const float*)d_in[17];
    const float* f_ngn      = (const float*)d_in[18];
    const float* f_c2w      = (const float*)d_in[19];
    const float* f_c2gn     = (const float*)d_in[20];
    const int* e1_hi = (const int*)d_in[21];
    const int* e1_wi = (const int*)d_in[22];
    const int* e2_hi = (const int*)d_in[23];
    const int* e2_wi = (const int*)d_in[24];
    const int* ps_u  = (const int*)d_in[25];
    const int* ps_v  = (const int*)d_in[26];
    const int* lr_u  = (const int*)d_in[27];
    const int* lr_v  = (const int*)d_in[28];
    float* out = (float*)d_out;

    // ---- workspace ----
    __bf16* gA   = (__bf16*)d_ws;                       // NG*128
    __bf16* gB   = gA + (size_t)NG * 128;               // NG*128
    __bf16* hbuf = gB + (size_t)NG * 128;               // E1_N*128
    __bf16* wbuf = hbuf + (size_t)E1_N * 128;           // 80*16384
    unsigned char* g8A = (unsigned char*)(wbuf + (size_t)80 * 16384); // NG*128 B
    unsigned char* g8B = g8A + (size_t)NG * 128;                      // NG*128 B
    int* ip      = (int*)(g8B + (size_t)NG * 128);
    int* cntA    = ip;             ip += NKEY;          // counters / fill heads
    int* rpAll   = ip;             ip += NKEY + 1;
    int* colAll  = ip;             ip += NEDGE;
    int* bsum    = ip;             ip += 256;

    dim3 blk(256), blk128(128);
    const dim3 gNG32((NG + 31) / 32), gNR32((NR + 31) / 32), gE32((E1_N + 31) / 32);

    // ---------------- weight prep ----------------
    PrepTab tab; int nw = 0;
    auto addw = [&](const float* p, int s) { tab.src[nw] = p; tab.stride[nw] = s; ++nw; };
    addw(lp_c1w, 256);                 // 0 c1A_0
    addw(lp_c1w + 128, 256);           // 1 c1B_0
    addw(lp_c1w + 32768, 256);         // 2 c1A_1
    addw(lp_c1w + 32768 + 128, 256);   // 3 c1B_1
    addw(lp_input_w + 16384, 128);     // 4 input_w[1]
    addw(lp_c2w, 128); addw(lp_c2w + 16384, 128);   // 5,6
    addw(lp_m1w, 128); addw(lp_m1w + 16384, 128);   // 7,8
    addw(lp_m2w, 128); addw(lp_m2w + 16384, 128);   // 9,10
    for (int i = 0; i < 4; ++i) addw(f_ctrw + (size_t)i * 16384, 128);      // 11..14
    for (int i = 0; i < 4; ++i)
        for (int k = 0; k < 12; ++k) addw(f_psw + ((size_t)i * 12 + k) * 16384, 128);
    for (int i = 0; i < 4; ++i) addw(f_lw + (size_t)i * 16384, 128);        // 63..66
    for (int i = 0; i < 4; ++i) addw(f_rw + (size_t)i * 16384, 128);        // 67..70
    for (int i = 0; i < 4; ++i) addw(f_c2w + (size_t)i * 16384, 128);       // 71..74
    tab.n = nw;
    auto wb = [&](int idx) { return (const __bf16*)(wbuf + (size_t)idx * 16384); };
    prepw_k<<<dim3((nw * 2048 + 255) / 256), blk, 0, stream>>>(tab, wbuf);

    // ---------------- combined CSR build (7 launches total) ----------------
    hipMemsetAsync(cntA, 0, (size_t)NKEY * 4, stream);
    histA_k<<<dim3((NEDGE + 255) / 256), blk, 0, stream>>>(ps_u, lr_u, e1_wi, e2_wi, cntA);
    {
        int n = NKEY, nb = (n + SCAN_CHUNK - 1) / SCAN_CHUNK;
        scan1_k<<<nb, blk, 0, stream>>>(cntA, n, bsum);
        scan2_k<<<1, blk, 0, stream>>>(bsum, nb);
        scan3_k<<<nb, blk, 0, stream>>>(cntA, n, bsum, rpAll);
    }
    hipMemcpyAsync(cntA, rpAll, (size_t)NKEY * 4, hipMemcpyDeviceToDevice, stream);
    fillA_k<<<dim3((NEDGE + 255) / 256), blk, 0, stream>>>(
        ps_u, lr_u, e1_wi, e2_wi, ps_v, lr_v, cntA, colAll);

    const int* rp14 = rpAll;                 // fusion keys [0, 14NG)
    const int* rpE1 = rpAll + 14 * NG;       // e1 keys
    const int* rpE2 = rpAll + 14 * NG + NG;  // e2 keys

    // ---------------- lane_pooling #1 (roi -> graph) ----------------
    edgefull_k<float><<<gE32, blk128, 0, stream>>>(
        e1_hi, e1_wi, roi_feat, roi_pose, graph_pose, lp_rpw, lp_rpb,
        wb(0), wb(1), lp_c1gn, hbuf, E1_N);
    lptail_k<false><<<gNG32, blk128, 0, stream>>>(
        hbuf, rpE1, colAll, nullptr, wb(5), nullptr, wb(7), wb(9),
        lp_ngn, lp_m1gn, lp_m2gn, gA, g8A, NG);

    // ---------------- global_graph: 4 fused layers ----------------
    for (int i = 0; i < 4; ++i) {
        FW fw;
        for (int k = 0; k < 12; ++k) fw.w[k] = wb(15 + i * 12 + k);
        fw.w[12] = wb(63 + i); fw.w[13] = wb(67 + i);
        fw.w[14] = wb(11 + i); fw.w[15] = wb(71 + i);
        const __bf16* src = (i & 1) ? gB : gA;
        __bf16* dst = (i & 1) ? gA : gB;
        const unsigned char* src8 = (i & 1) ? g8B : g8A;
        unsigned char* dst8 = (i & 1) ? g8A : g8B;
        fusedlayer_k<<<gNG32, blk128, 0, stream>>>(
            src, src8, rp14, colAll, fw, f_ngn + (size_t)i * 256,
            f_c2gn + (size_t)i * 256, dst, dst8, NG);
    }
    // after i=3: result in gA

    // ---------------- lane_pooling #2 (graph -> roi) ----------------
    edgefull_k<__bf16><<<gE32, blk128, 0, stream>>>(
        e2_hi, e2_wi, gA, graph_pose, roi_pose, lp_rpw + 512, lp_rpb + 128,
        wb(2), wb(3), lp_c1gn + 256, hbuf, E2_N);
    lptail_k<true><<<gNR32, blk128, 0, stream>>>(
        hbuf, rpE2, colAll, roi_feat, wb(6), wb(4), wb(8), wb(10),
        lp_ngn + 256, lp_m1gn + 256, lp_m2gn + 256, out, nullptr, NR);
}